// Round 5
// baseline (150.273 us; speedup 1.0000x reference)
//
#include <hip/hip_runtime.h>
#include <math.h>

#define NPATCH 2048
#define NPTS 1024
#define NTOT (NPATCH * NPTS)

// ---------------------------------------------------------------------------
// One block per patch, 384 threads (6 waves).
//   phase 1: geometry, <=3 points/thread (xyz/opac/rot written immediately)
//   phase 2: in-block area reduction -> scaling writes
//   phase 3: SH stage1 tmp[i][l][c] = sum_k bu[i][k]*sh[k*4+l][c]  (LDS)
//   phase 4: SH stage2 — thread owns (i,c), tmp rows in REGISTERS,
//            j-loop produces 32 float4 stores (tmp reuse x32, LDS ~0)
// ---------------------------------------------------------------------------
__global__ __launch_bounds__(384) void spline_all(
    const float* __restrict__ cp,       // [P,4,4,3]
    const float* __restrict__ Wt,       // [P,4,4]
    const float* __restrict__ sh_dc,    // [P,4,4,1,3]
    const float* __restrict__ sh_rest,  // [P,4,4,15,3]
    const float* __restrict__ spar,     // [P,2]
    const float* __restrict__ opac,     // [N,1]
    const float* __restrict__ b_u,      // [P,32,4]
    const float* __restrict__ b_v,
    const float* __restrict__ db_u,
    const float* __restrict__ db_v,
    const float* __restrict__ ddb_u,
    const float* __restrict__ ddb_v,
    float* __restrict__ out)
{
    const int a = blockIdx.x;
    const int t = threadIdx.x;

    __shared__ float  s_W[16];
    __shared__ float  s_wcp[16][3];
    __shared__ float  s_bu[32][4];
    __shared__ float  s_bv[32][4];
    __shared__ float  s_dbu[32][4];
    __shared__ float  s_dbv[32][4];
    __shared__ float  s_ddbu[32][4];
    __shared__ float  s_ddbv[32][4];
    __shared__ float  s_sh[16][48];
    __shared__ float4 s_tmp4[32 * 53];   // [i][l][c]: idx = i*53 + l*13 + c
    __shared__ float  s_red[6];
    __shared__ float  s_area;

    // ---- stage inputs ----
    if (t < 16) s_W[t] = Wt[a * 16 + t];
    if (t < 48) {
        const int kl = t / 3, m = t - kl * 3;
        s_wcp[kl][m] = cp[a * 48 + t] * Wt[a * 16 + kl];
    }
    if (t < 128) {
        s_bu  [t >> 2][t & 3] = b_u  [a * 128 + t];
        s_bv  [t >> 2][t & 3] = b_v  [a * 128 + t];
        s_dbu [t >> 2][t & 3] = db_u [a * 128 + t];
        s_dbv [t >> 2][t & 3] = db_v [a * 128 + t];
        s_ddbu[t >> 2][t & 3] = ddb_u[a * 128 + t];
        s_ddbv[t >> 2][t & 3] = ddb_v[a * 128 + t];
    }
    for (int idx = t; idx < 768; idx += 384) {
        const int kl = idx / 48, c = idx - kl * 48;
        s_sh[kl][c] = (c < 3) ? sh_dc[a * 48 + kl * 3 + c]
                              : sh_rest[a * 720 + kl * 45 + (c - 3)];
    }
    __syncthreads();

    const long N3 = 3L * NTOT, N4 = 4L * NTOT, N7 = 7L * NTOT;

    // ---- phase 1: geometry ----
    float sxA[3], syA[3], cvxA[3], cvyA[3];
    float area_acc = 0.f;

    #pragma unroll
    for (int r = 0; r < 3; ++r) {
        const int p = t + r * 384;
        if (p < NPTS) {
            const int i = p >> 5, j = p & 31;

            float den = 0.f;
            float x0 = 0, x1 = 0, x2 = 0;
            float du0 = 0, du1 = 0, du2 = 0, dv0 = 0, dv1 = 0, dv2 = 0;
            float eu0 = 0, eu1 = 0, eu2 = 0, ev0 = 0, ev1 = 0, ev2 = 0;
            #pragma unroll
            for (int kl = 0; kl < 16; ++kl) {
                const int k = kl >> 2, l = kl & 3;
                const float bb  = s_bu[i][k] * s_bv[j][l];
                const float wdu = s_dbu[i][k] * s_bv[j][l];
                const float wdv = s_bu[i][k] * s_dbv[j][l];
                const float weu = s_ddbu[i][k] * s_bv[j][l];
                const float wev = s_bu[i][k] * s_ddbv[j][l];
                den += bb * s_W[kl];
                const float c0 = s_wcp[kl][0], c1 = s_wcp[kl][1], c2 = s_wcp[kl][2];
                x0  += bb  * c0; x1  += bb  * c1; x2  += bb  * c2;
                du0 += wdu * c0; du1 += wdu * c1; du2 += wdu * c2;
                dv0 += wdv * c0; dv1 += wdv * c1; dv2 += wdv * c2;
                eu0 += weu * c0; eu1 += weu * c1; eu2 += weu * c2;
                ev0 += wev * c0; ev1 += wev * c1; ev2 += wev * c2;
            }
            if (den == 0.f) den = 1.f;
            const float inv = 1.0f / den;
            x0 *= inv; x1 *= inv; x2 *= inv;
            du0 *= inv; du1 *= inv; du2 *= inv;
            dv0 *= inv; dv1 *= inv; dv2 *= inv;
            eu0 *= inv; eu1 *= inv; eu2 *= inv;
            ev0 *= inv; ev1 *= inv; ev2 *= inv;

            const float cx = du1 * dv2 - du2 * dv1;
            const float cy = du2 * dv0 - du0 * dv2;
            const float cz = du0 * dv1 - du1 * dv0;
            area_acc += sqrtf(cx * cx + cy * cy + cz * cz);

            float l1 = fabsf(cx) + fabsf(cy) + fabsf(cz);
            l1 = fmaxf(l1, 1e-12f);
            float nx = cx / l1, ny = cy / l1, nz = cz / l1;
            float l2 = sqrtf(nx * nx + ny * ny + nz * nz);
            l2 = fmaxf(l2, 1e-12f);
            nx /= l2; ny /= l2; nz /= l2;
            const float qw = 1.f + nz, qx = -ny, qy = nx;
            float qn = sqrtf(qw * qw + qx * qx + qy * qy);
            qn = fmaxf(qn, 1e-12f);
            const float rqn = 1.0f / qn;

            sxA[r]  = du0 * du0 + du1 * du1 + du2 * du2 + 10.f;
            syA[r]  = dv0 * dv0 + dv1 * dv1 + dv2 * dv2 + 10.f;
            cvxA[r] = eu0 + eu1 + eu2;
            cvyA[r] = ev0 + ev1 + ev2;

            const long n = (long)a * NPTS + p;
            out[n * 3 + 0] = x0;
            out[n * 3 + 1] = x1;
            out[n * 3 + 2] = x2;
            out[N3 + n] = opac[n];
            *reinterpret_cast<float4*>(out + N7 + n * 4) =
                make_float4(qw * rqn, qx * rqn, qy * rqn, 0.f);
        }
    }

    // ---- phase 2: area reduction (6 waves), then scaling writes ----
    #pragma unroll
    for (int off = 32; off > 0; off >>= 1)
        area_acc += __shfl_down(area_acc, off, 64);
    if ((t & 63) == 0) s_red[t >> 6] = area_acc;
    __syncthreads();
    if (t == 0)
        s_area = s_red[0] + s_red[1] + s_red[2] + s_red[3] + s_red[4] + s_red[5];
    __syncthreads();

    {
        const float factor = s_area * (1.0f / 1024.0f) * (1.0f / 1024.0f);
        const float sp0 = spar[a * 2 + 0], sp1 = spar[a * 2 + 1];
        const float sf0 = factor * sp0;
        const float sf1 = factor * sp1;
        const float sf2 = factor * 1e-16f;
        const float sc2 = 0.5f * __logf(fabsf(sf2 * 10.f)) - __logf(11.f);

        #pragma unroll
        for (int r = 0; r < 3; ++r) {
            const int p = t + r * 384;
            if (p < NPTS) {
                const long n = (long)a * NPTS + p;
                out[N4 + n * 3 + 0] =
                    0.5f * __logf(fabsf(sf0 * sxA[r])) - __logf(fabsf(cvxA[r]) + 10.f);
                out[N4 + n * 3 + 1] =
                    0.5f * __logf(fabsf(sf1 * syA[r])) - __logf(fabsf(cvyA[r]) + 10.f);
                out[N4 + n * 3 + 2] = sc2;
            }
        }
    }

    // ---- phase 3: SH stage1 -> s_tmp4 (1536 float4 = 4 per thread) ----
    #pragma unroll
    for (int r = 0; r < 4; ++r) {
        const int e4 = t + r * 384;
        const int i = e4 / 48, rem = e4 - i * 48;
        const int l = rem / 12, cq = rem - l * 12;
        float ax = 0.f, ay = 0.f, az = 0.f, aw = 0.f;
        #pragma unroll
        for (int k = 0; k < 4; ++k) {
            const float w = s_bu[i][k];
            const float4 v = *reinterpret_cast<const float4*>(&s_sh[k * 4 + l][cq * 4]);
            ax += w * v.x; ay += w * v.y; az += w * v.z; aw += w * v.w;
        }
        s_tmp4[i * 53 + l * 13 + cq] = make_float4(ax, ay, az, aw);
    }
    __syncthreads();

    // ---- phase 4: SH stage2 — thread owns (i,c); tmp rows in registers ----
    {
        const int i = t / 12;          // 0..31
        const int c = t - i * 12;      // 0..11
        const float4 t0 = s_tmp4[i * 53 + 0 * 13 + c];
        const float4 t1 = s_tmp4[i * 53 + 1 * 13 + c];
        const float4 t2 = s_tmp4[i * 53 + 2 * 13 + c];
        const float4 t3 = s_tmp4[i * 53 + 3 * 13 + c];

        float4* __restrict__ out4 =
            reinterpret_cast<float4*>(out + 11L * NTOT) + (long)a * 12288 + i * 384 + c;

        #pragma unroll 4
        for (int j = 0; j < 32; ++j) {
            const float4 bv = *reinterpret_cast<const float4*>(s_bv[j]);
            out4[j * 12] = make_float4(
                bv.x * t0.x + bv.y * t1.x + bv.z * t2.x + bv.w * t3.x,
                bv.x * t0.y + bv.y * t1.y + bv.z * t2.y + bv.w * t3.y,
                bv.x * t0.z + bv.y * t1.z + bv.z * t2.z + bv.w * t3.z,
                bv.x * t0.w + bv.y * t1.w + bv.z * t2.w + bv.w * t3.w);
        }
    }
}

extern "C" void kernel_launch(void* const* d_in, const int* in_sizes, int n_in,
                              void* d_out, int out_size, void* d_ws, size_t ws_size,
                              hipStream_t stream) {
    const float* cp      = (const float*)d_in[0];
    const float* Wt      = (const float*)d_in[1];
    const float* sh_dc   = (const float*)d_in[2];
    const float* sh_rest = (const float*)d_in[3];
    const float* spar    = (const float*)d_in[4];
    const float* opac    = (const float*)d_in[5];
    const float* b_u     = (const float*)d_in[6];
    const float* b_v     = (const float*)d_in[7];
    const float* db_u    = (const float*)d_in[8];
    const float* db_v    = (const float*)d_in[9];
    const float* ddb_u   = (const float*)d_in[10];
    const float* ddb_v   = (const float*)d_in[11];
    float* out = (float*)d_out;

    hipLaunchKernelGGL(spline_all, dim3(NPATCH), dim3(384), 0, stream,
                       cp, Wt, sh_dc, sh_rest, spar, opac,
                       b_u, b_v, db_u, db_v, ddb_u, ddb_v, out);
}

// Round 6
// 145.481 us; speedup vs baseline: 1.0329x; 1.0329x over previous
//
#include <hip/hip_runtime.h>
#include <math.h>

#define NPATCH 2048
#define NPTS 1024
#define NTOT (NPATCH * NPTS)

// ---------------------------------------------------------------------------
// Prologue: per-patch area sum -> ws[a]. (validated in R4)
// ---------------------------------------------------------------------------
__global__ __launch_bounds__(256) void area_kernel(
    const float* __restrict__ cp,       // [P,4,4,3]
    const float* __restrict__ Wt,       // [P,4,4]
    const float* __restrict__ b_u,      // [P,32,4]
    const float* __restrict__ b_v,
    const float* __restrict__ db_u,
    const float* __restrict__ db_v,
    float* __restrict__ ws)
{
    const int a = blockIdx.x;
    const int tid = threadIdx.x;

    __shared__ float s_W[16];
    __shared__ float s_wcp[16][3];
    __shared__ float s_bu[32][4];
    __shared__ float s_bv[32][4];
    __shared__ float s_dbu[32][4];
    __shared__ float s_dbv[32][4];
    __shared__ float s_red[4];

    if (tid < 16) s_W[tid] = Wt[a * 16 + tid];
    if (tid < 48) {
        const int kl = tid / 3, m = tid - kl * 3;
        s_wcp[kl][m] = cp[a * 48 + tid] * Wt[a * 16 + kl];
    }
    if (tid < 128) {
        s_bu [tid >> 2][tid & 3] = b_u [a * 128 + tid];
        s_bv [tid >> 2][tid & 3] = b_v [a * 128 + tid];
        s_dbu[tid >> 2][tid & 3] = db_u[a * 128 + tid];
        s_dbv[tid >> 2][tid & 3] = db_v[a * 128 + tid];
    }
    __syncthreads();

    float acc = 0.f;
    #pragma unroll
    for (int s2 = 0; s2 < 4; ++s2) {
        const int pp = tid + s2 * 256;
        const int i = pp >> 5, j = pp & 31;
        float den = 0.f;
        float du0 = 0, du1 = 0, du2 = 0, dv0 = 0, dv1 = 0, dv2 = 0;
        #pragma unroll
        for (int kl = 0; kl < 16; ++kl) {
            const int k = kl >> 2, l = kl & 3;
            const float bb  = s_bu[i][k] * s_bv[j][l];
            const float wdu = s_dbu[i][k] * s_bv[j][l];
            const float wdv = s_bu[i][k] * s_dbv[j][l];
            den += bb * s_W[kl];
            const float c0 = s_wcp[kl][0], c1 = s_wcp[kl][1], c2 = s_wcp[kl][2];
            du0 += wdu * c0; du1 += wdu * c1; du2 += wdu * c2;
            dv0 += wdv * c0; dv1 += wdv * c1; dv2 += wdv * c2;
        }
        if (den == 0.f) den = 1.f;
        const float inv = 1.0f / den;
        const float cx = du1 * dv2 - du2 * dv1;
        const float cy = du2 * dv0 - du0 * dv2;
        const float cz = du0 * dv1 - du1 * dv0;
        acc += sqrtf(cx * cx + cy * cy + cz * cz) * inv * inv;
    }

    #pragma unroll
    for (int off = 32; off > 0; off >>= 1)
        acc += __shfl_down(acc, off, 64);
    if ((tid & 63) == 0) s_red[tid >> 6] = acc;
    __syncthreads();
    if (tid == 0) ws[a] = s_red[0] + s_red[1] + s_red[2] + s_red[3];
}

// ---------------------------------------------------------------------------
// Main kernel: 12288 blocks x 256 threads, parity-interleaved block roles.
//   blk%3==0      : SH half-patch  (4096 blocks; 2 per patch)
//   blk%3 in {1,2}: geometry quarter-patch (8192 blocks; 4 per patch)
// Mixed residency per CU keeps HBM stores flowing under VALU work.
// ---------------------------------------------------------------------------
__global__ __launch_bounds__(256) void main_kernel(
    const float* __restrict__ cp,       // [P,4,4,3]
    const float* __restrict__ Wt,       // [P,4,4]
    const float* __restrict__ sh_dc,    // [P,4,4,1,3]
    const float* __restrict__ sh_rest,  // [P,4,4,15,3]
    const float* __restrict__ spar,     // [P,2]
    const float* __restrict__ opac,     // [N,1]
    const float* __restrict__ b_u,      // [P,32,4]
    const float* __restrict__ b_v,
    const float* __restrict__ db_u,
    const float* __restrict__ db_v,
    const float* __restrict__ ddb_u,
    const float* __restrict__ ddb_v,
    const float* __restrict__ ws,
    float* __restrict__ out)
{
    __shared__ __align__(16) float sm[4352];   // 17.4 KB union

    const int blk = blockIdx.x;
    const int t = threadIdx.x;
    const int r3 = blk % 3;
    const int s  = blk / 3;

    if (r3 == 0) {
        // -------------------- SH half-patch --------------------
        const int a = s >> 1, half = s & 1;

        float*  s_sh  = sm;                       // [16][48]  768 floats
        float*  s_bu  = sm + 768;                 // 16 rows x4 = 64
        float*  s_bv  = sm + 832;                 // 32 rows x4 = 128
        float4* s_tmp = (float4*)(sm + 960);      // 848 float4 (i*53+l*13+c)

        for (int idx = t; idx < 768; idx += 256) {
            const int kl = idx / 48, c = idx - kl * 48;
            s_sh[kl * 48 + c] = (c < 3) ? sh_dc[a * 48 + kl * 3 + c]
                                        : sh_rest[a * 720 + kl * 45 + (c - 3)];
        }
        if (t < 64)  s_bu[t] = b_u[a * 128 + half * 64 + t];
        if (t < 128) s_bv[t] = b_v[a * 128 + t];
        __syncthreads();

        // stage 1: tmp[i][l][c] = sum_k bu[i][k] * sh[k*4+l][c*4..]
        #pragma unroll
        for (int r = 0; r < 3; ++r) {
            const int e = t + r * 256;            // 0..767
            const int i = e / 48, rem = e - i * 48;
            const int l = rem / 12, cq = rem - l * 12;
            float ax = 0.f, ay = 0.f, az = 0.f, aw = 0.f;
            #pragma unroll
            for (int k = 0; k < 4; ++k) {
                const float w = s_bu[i * 4 + k];
                const float4 v = *reinterpret_cast<const float4*>(
                    &s_sh[(k * 4 + l) * 48 + cq * 4]);
                ax += w * v.x; ay += w * v.y; az += w * v.z; aw += w * v.w;
            }
            s_tmp[i * 53 + l * 13 + cq] = make_float4(ax, ay, az, aw);
        }
        __syncthreads();

        // stage 2: thread owns (i,c); tmp rows in registers; 32 j-stores
        if (t < 192) {
            const int i = t / 12;          // local 0..15
            const int c = t - i * 12;      // 0..11
            const float4 t0 = s_tmp[i * 53 + 0 * 13 + c];
            const float4 t1 = s_tmp[i * 53 + 1 * 13 + c];
            const float4 t2 = s_tmp[i * 53 + 2 * 13 + c];
            const float4 t3 = s_tmp[i * 53 + 3 * 13 + c];

            float4* __restrict__ out4 =
                reinterpret_cast<float4*>(out + 11L * NTOT) +
                (long)a * 12288 + (half * 16 + i) * 384 + c;

            #pragma unroll 4
            for (int j = 0; j < 32; ++j) {
                const float4 bv = reinterpret_cast<const float4*>(s_bv)[j];
                out4[j * 12] = make_float4(
                    bv.x * t0.x + bv.y * t1.x + bv.z * t2.x + bv.w * t3.x,
                    bv.x * t0.y + bv.y * t1.y + bv.z * t2.y + bv.w * t3.y,
                    bv.x * t0.z + bv.y * t1.z + bv.z * t2.z + bv.w * t3.z,
                    bv.x * t0.w + bv.y * t1.w + bv.z * t2.w + bv.w * t3.w);
            }
        }
    } else {
        // -------------------- geometry quarter-patch --------------------
        const int g = s * 2 + (r3 - 1);    // 0..8191
        const int a = g >> 2, q = g & 3;

        float* g_W    = sm;          // 16
        float* g_wcp  = sm + 16;     // 48  [kl*3+m]
        float* g_bu   = sm + 64;     // 32  (8 rows)
        float* g_dbu  = sm + 96;     // 32
        float* g_ddbu = sm + 128;    // 32
        float* g_bv   = sm + 160;    // 128
        float* g_dbv  = sm + 288;    // 128
        float* g_ddbv = sm + 416;    // 128

        if (t < 16) g_W[t] = Wt[a * 16 + t];
        if (t < 48) {
            const int kl = t / 3;
            g_wcp[t] = cp[a * 48 + t] * Wt[a * 16 + kl];
        }
        if (t < 32) {
            g_bu  [t] = b_u  [a * 128 + q * 32 + t];
            g_dbu [t] = db_u [a * 128 + q * 32 + t];
            g_ddbu[t] = ddb_u[a * 128 + q * 32 + t];
        }
        if (t < 128) {
            g_bv  [t] = b_v  [a * 128 + t];
            g_dbv [t] = db_v [a * 128 + t];
            g_ddbv[t] = ddb_v[a * 128 + t];
        }
        __syncthreads();

        const long N3 = 3L * NTOT, N4 = 4L * NTOT, N7 = 7L * NTOT;

        const int i = t >> 5, j = t & 31;   // local u-row (0..7), v-col
        float bu[4], bv[4], dbu_[4], dbv_[4], ddbu_[4], ddbv_[4];
        #pragma unroll
        for (int k = 0; k < 4; ++k) {
            bu[k]    = g_bu[i * 4 + k];    bv[k]    = g_bv[j * 4 + k];
            dbu_[k]  = g_dbu[i * 4 + k];   dbv_[k]  = g_dbv[j * 4 + k];
            ddbu_[k] = g_ddbu[i * 4 + k];  ddbv_[k] = g_ddbv[j * 4 + k];
        }

        float den = 0.f;
        float x0 = 0, x1 = 0, x2 = 0;
        float du0 = 0, du1 = 0, du2 = 0, dv0 = 0, dv1 = 0, dv2 = 0;
        float eu0 = 0, eu1 = 0, eu2 = 0, ev0 = 0, ev1 = 0, ev2 = 0;
        #pragma unroll
        for (int kl = 0; kl < 16; ++kl) {
            const int k = kl >> 2, l = kl & 3;
            const float bb  = bu[k] * bv[l];
            const float wdu = dbu_[k] * bv[l];
            const float wdv = bu[k] * dbv_[l];
            const float weu = ddbu_[k] * bv[l];
            const float wev = bu[k] * ddbv_[l];
            den += bb * g_W[kl];
            const float c0 = g_wcp[kl * 3 + 0], c1 = g_wcp[kl * 3 + 1],
                        c2 = g_wcp[kl * 3 + 2];
            x0  += bb  * c0; x1  += bb  * c1; x2  += bb  * c2;
            du0 += wdu * c0; du1 += wdu * c1; du2 += wdu * c2;
            dv0 += wdv * c0; dv1 += wdv * c1; dv2 += wdv * c2;
            eu0 += weu * c0; eu1 += weu * c1; eu2 += weu * c2;
            ev0 += wev * c0; ev1 += wev * c1; ev2 += wev * c2;
        }
        if (den == 0.f) den = 1.f;
        const float inv = 1.0f / den;
        x0 *= inv; x1 *= inv; x2 *= inv;
        du0 *= inv; du1 *= inv; du2 *= inv;
        dv0 *= inv; dv1 *= inv; dv2 *= inv;
        eu0 *= inv; eu1 *= inv; eu2 *= inv;
        ev0 *= inv; ev1 *= inv; ev2 *= inv;

        const float cx = du1 * dv2 - du2 * dv1;
        const float cy = du2 * dv0 - du0 * dv2;
        const float cz = du0 * dv1 - du1 * dv0;

        float l1 = fabsf(cx) + fabsf(cy) + fabsf(cz);
        l1 = fmaxf(l1, 1e-12f);
        float nx = cx / l1, ny = cy / l1, nz = cz / l1;
        float l2 = sqrtf(nx * nx + ny * ny + nz * nz);
        l2 = fmaxf(l2, 1e-12f);
        nx /= l2; ny /= l2; nz /= l2;
        const float qw = 1.f + nz, qx = -ny, qy = nx;
        float qn = sqrtf(qw * qw + qx * qx + qy * qy);
        qn = fmaxf(qn, 1e-12f);
        const float rqn = 1.0f / qn;

        const float sx  = du0 * du0 + du1 * du1 + du2 * du2 + 10.f;
        const float sy  = dv0 * dv0 + dv1 * dv1 + dv2 * dv2 + 10.f;
        const float cvx = eu0 + eu1 + eu2;
        const float cvy = ev0 + ev1 + ev2;

        const float factor = ws[a] * (1.0f / 1024.0f) * (1.0f / 1024.0f);
        const float sp0 = spar[a * 2 + 0], sp1 = spar[a * 2 + 1];
        const float sf0 = factor * sp0;
        const float sf1 = factor * sp1;
        const float sf2 = factor * 1e-16f;

        const long n = (long)a * NPTS + q * 256 + t;
        out[n * 3 + 0] = x0;
        out[n * 3 + 1] = x1;
        out[n * 3 + 2] = x2;
        out[N3 + n] = opac[n];
        *reinterpret_cast<float4*>(out + N7 + n * 4) =
            make_float4(qw * rqn, qx * rqn, qy * rqn, 0.f);

        const float sc0 = 0.5f * __logf(fabsf(sf0 * sx)) - __logf(fabsf(cvx) + 10.f);
        const float sc1 = 0.5f * __logf(fabsf(sf1 * sy)) - __logf(fabsf(cvy) + 10.f);
        const float sc2 = 0.5f * __logf(fabsf(sf2 * 10.f)) - __logf(11.f);
        out[N4 + n * 3 + 0] = sc0;
        out[N4 + n * 3 + 1] = sc1;
        out[N4 + n * 3 + 2] = sc2;
    }
}

extern "C" void kernel_launch(void* const* d_in, const int* in_sizes, int n_in,
                              void* d_out, int out_size, void* d_ws, size_t ws_size,
                              hipStream_t stream) {
    const float* cp      = (const float*)d_in[0];
    const float* Wt      = (const float*)d_in[1];
    const float* sh_dc   = (const float*)d_in[2];
    const float* sh_rest = (const float*)d_in[3];
    const float* spar    = (const float*)d_in[4];
    const float* opac    = (const float*)d_in[5];
    const float* b_u     = (const float*)d_in[6];
    const float* b_v     = (const float*)d_in[7];
    const float* db_u    = (const float*)d_in[8];
    const float* db_v    = (const float*)d_in[9];
    const float* ddb_u   = (const float*)d_in[10];
    const float* ddb_v   = (const float*)d_in[11];
    float* out = (float*)d_out;
    float* ws  = (float*)d_ws;

    hipLaunchKernelGGL(area_kernel, dim3(NPATCH), dim3(256), 0, stream,
                       cp, Wt, b_u, b_v, db_u, db_v, ws);
    hipLaunchKernelGGL(main_kernel, dim3(12288), dim3(256), 0, stream,
                       cp, Wt, sh_dc, sh_rest, spar, opac,
                       b_u, b_v, db_u, db_v, ddb_u, ddb_v, ws, out);
}

// Round 7
// 144.870 us; speedup vs baseline: 1.0373x; 1.0042x over previous
//
#include <hip/hip_runtime.h>
#include <math.h>

#define NPATCH 2048
#define NPTS 1024
#define NTOT (NPATCH * NPTS)

// ---------------------------------------------------------------------------
// Kernel 1: per-patch area sum -> ws[a]. (validated R4, unchanged)
// ---------------------------------------------------------------------------
__global__ __launch_bounds__(256) void area_kernel(
    const float* __restrict__ cp,       // [P,4,4,3]
    const float* __restrict__ Wt,       // [P,4,4]
    const float* __restrict__ b_u,      // [P,32,4]
    const float* __restrict__ b_v,
    const float* __restrict__ db_u,
    const float* __restrict__ db_v,
    float* __restrict__ ws)
{
    const int a = blockIdx.x;
    const int tid = threadIdx.x;

    __shared__ float s_W[16];
    __shared__ float s_wcp[16][3];
    __shared__ float s_bu[32][4];
    __shared__ float s_bv[32][4];
    __shared__ float s_dbu[32][4];
    __shared__ float s_dbv[32][4];
    __shared__ float s_red[4];

    if (tid < 16) s_W[tid] = Wt[a * 16 + tid];
    if (tid < 48) {
        const int kl = tid / 3, m = tid - kl * 3;
        s_wcp[kl][m] = cp[a * 48 + tid] * Wt[a * 16 + kl];
    }
    if (tid < 128) {
        s_bu [tid >> 2][tid & 3] = b_u [a * 128 + tid];
        s_bv [tid >> 2][tid & 3] = b_v [a * 128 + tid];
        s_dbu[tid >> 2][tid & 3] = db_u[a * 128 + tid];
        s_dbv[tid >> 2][tid & 3] = db_v[a * 128 + tid];
    }
    __syncthreads();

    float acc = 0.f;
    #pragma unroll
    for (int s2 = 0; s2 < 4; ++s2) {
        const int pp = tid + s2 * 256;
        const int i = pp >> 5, j = pp & 31;
        float den = 0.f;
        float du0 = 0, du1 = 0, du2 = 0, dv0 = 0, dv1 = 0, dv2 = 0;
        #pragma unroll
        for (int kl = 0; kl < 16; ++kl) {
            const int k = kl >> 2, l = kl & 3;
            const float bb  = s_bu[i][k] * s_bv[j][l];
            const float wdu = s_dbu[i][k] * s_bv[j][l];
            const float wdv = s_bu[i][k] * s_dbv[j][l];
            den += bb * s_W[kl];
            const float c0 = s_wcp[kl][0], c1 = s_wcp[kl][1], c2 = s_wcp[kl][2];
            du0 += wdu * c0; du1 += wdu * c1; du2 += wdu * c2;
            dv0 += wdv * c0; dv1 += wdv * c1; dv2 += wdv * c2;
        }
        if (den == 0.f) den = 1.f;
        const float inv = 1.0f / den;
        const float cx = du1 * dv2 - du2 * dv1;
        const float cy = du2 * dv0 - du0 * dv2;
        const float cz = du0 * dv1 - du1 * dv0;
        acc += sqrtf(cx * cx + cy * cy + cz * cz) * inv * inv;
    }

    #pragma unroll
    for (int off = 32; off > 0; off >>= 1)
        acc += __shfl_down(acc, off, 64);
    if ((tid & 63) == 0) s_red[tid >> 6] = acc;
    __syncthreads();
    if (tid == 0) ws[a] = s_red[0] + s_red[1] + s_red[2] + s_red[3];
}

// ---------------------------------------------------------------------------
// Kernel 2: geometry quarter-patch, 1 pt/thread. ALL stores full-width bursts:
//   rot: direct float4; xyz/scaling: staged in LDS -> 1024B wave stores;
//   opacity: float4 copy by first 64 threads.
// ---------------------------------------------------------------------------
__global__ __launch_bounds__(256) void geom_kernel(
    const float* __restrict__ cp,       // [P,4,4,3]
    const float* __restrict__ Wt,       // [P,4,4]
    const float* __restrict__ spar,     // [P,2]
    const float* __restrict__ opac,     // [N,1]
    const float* __restrict__ b_u,      // [P,32,4]
    const float* __restrict__ b_v,
    const float* __restrict__ db_u,
    const float* __restrict__ db_v,
    const float* __restrict__ ddb_u,
    const float* __restrict__ ddb_v,
    const float* __restrict__ ws,
    float* __restrict__ out)
{
    const int blk = blockIdx.x;
    const int a = blk >> 2, q = blk & 3;
    const int t = threadIdx.x;

    __shared__ float g_W[16];
    __shared__ float g_wcp[16][3];
    __shared__ float g_bu[8][4];
    __shared__ float g_dbu[8][4];
    __shared__ float g_ddbu[8][4];
    __shared__ float g_bv[32][4];
    __shared__ float g_dbv[32][4];
    __shared__ float g_ddbv[32][4];
    __shared__ __align__(16) float s_xyz[768];
    __shared__ __align__(16) float s_scl[768];

    if (t < 16) g_W[t] = Wt[a * 16 + t];
    if (t < 48) {
        const int kl = t / 3, m = t - kl * 3;
        g_wcp[kl][m] = cp[a * 48 + t] * Wt[a * 16 + kl];
    }
    if (t < 32) {
        g_bu  [t >> 2][t & 3] = b_u  [a * 128 + q * 32 + t];
        g_dbu [t >> 2][t & 3] = db_u [a * 128 + q * 32 + t];
        g_ddbu[t >> 2][t & 3] = ddb_u[a * 128 + q * 32 + t];
    }
    if (t < 128) {
        g_bv  [t >> 2][t & 3] = b_v  [a * 128 + t];
        g_dbv [t >> 2][t & 3] = db_v [a * 128 + t];
        g_ddbv[t >> 2][t & 3] = ddb_v[a * 128 + t];
    }
    __syncthreads();

    const long N3 = 3L * NTOT, N4 = 4L * NTOT, N7 = 7L * NTOT;
    const long n0 = (long)a * NPTS + q * 256;      // first point of this block
    const long n  = n0 + t;

    const int i = t >> 5, j = t & 31;
    float bu[4], bv[4], dbu_[4], dbv_[4], ddbu_[4], ddbv_[4];
    #pragma unroll
    for (int k = 0; k < 4; ++k) {
        bu[k]    = g_bu[i][k];    bv[k]    = g_bv[j][k];
        dbu_[k]  = g_dbu[i][k];   dbv_[k]  = g_dbv[j][k];
        ddbu_[k] = g_ddbu[i][k];  ddbv_[k] = g_ddbv[j][k];
    }

    float den = 0.f;
    float x0 = 0, x1 = 0, x2 = 0;
    float du0 = 0, du1 = 0, du2 = 0, dv0 = 0, dv1 = 0, dv2 = 0;
    float eu0 = 0, eu1 = 0, eu2 = 0, ev0 = 0, ev1 = 0, ev2 = 0;
    #pragma unroll
    for (int kl = 0; kl < 16; ++kl) {
        const int k = kl >> 2, l = kl & 3;
        const float bb  = bu[k] * bv[l];
        const float wdu = dbu_[k] * bv[l];
        const float wdv = bu[k] * dbv_[l];
        const float weu = ddbu_[k] * bv[l];
        const float wev = bu[k] * ddbv_[l];
        den += bb * g_W[kl];
        const float c0 = g_wcp[kl][0], c1 = g_wcp[kl][1], c2 = g_wcp[kl][2];
        x0  += bb  * c0; x1  += bb  * c1; x2  += bb  * c2;
        du0 += wdu * c0; du1 += wdu * c1; du2 += wdu * c2;
        dv0 += wdv * c0; dv1 += wdv * c1; dv2 += wdv * c2;
        eu0 += weu * c0; eu1 += weu * c1; eu2 += weu * c2;
        ev0 += wev * c0; ev1 += wev * c1; ev2 += wev * c2;
    }
    if (den == 0.f) den = 1.f;
    const float inv = 1.0f / den;
    x0 *= inv; x1 *= inv; x2 *= inv;
    du0 *= inv; du1 *= inv; du2 *= inv;
    dv0 *= inv; dv1 *= inv; dv2 *= inv;
    eu0 *= inv; eu1 *= inv; eu2 *= inv;
    ev0 *= inv; ev1 *= inv; ev2 *= inv;

    const float cx = du1 * dv2 - du2 * dv1;
    const float cy = du2 * dv0 - du0 * dv2;
    const float cz = du0 * dv1 - du1 * dv0;

    float l1 = fabsf(cx) + fabsf(cy) + fabsf(cz);
    l1 = fmaxf(l1, 1e-12f);
    float nx = cx / l1, ny = cy / l1, nz = cz / l1;
    float l2 = sqrtf(nx * nx + ny * ny + nz * nz);
    l2 = fmaxf(l2, 1e-12f);
    nx /= l2; ny /= l2; nz /= l2;
    const float qw = 1.f + nz, qx = -ny, qy = nx;
    float qn = sqrtf(qw * qw + qx * qx + qy * qy);
    qn = fmaxf(qn, 1e-12f);
    const float rqn = 1.0f / qn;

    // rotation: already lane-contiguous float4 -> direct store
    *reinterpret_cast<float4*>(out + N7 + n * 4) =
        make_float4(qw * rqn, qx * rqn, qy * rqn, 0.f);

    // opacity: float4 copy (64 threads cover 256 points)
    if (t < 64)
        reinterpret_cast<float4*>(out + N3 + n0)[t] =
            reinterpret_cast<const float4*>(opac + n0)[t];

    const float sx  = du0 * du0 + du1 * du1 + du2 * du2 + 10.f;
    const float sy  = dv0 * dv0 + dv1 * dv1 + dv2 * dv2 + 10.f;
    const float cvx = eu0 + eu1 + eu2;
    const float cvy = ev0 + ev1 + ev2;

    const float factor = ws[a] * (1.0f / 1024.0f) * (1.0f / 1024.0f);
    const float sp0 = spar[a * 2 + 0], sp1 = spar[a * 2 + 1];
    const float sf0 = factor * sp0;
    const float sf1 = factor * sp1;
    const float sf2 = factor * 1e-16f;

    // stage xyz + scaling in LDS, then emit full 1024B wave bursts
    s_xyz[t * 3 + 0] = x0;
    s_xyz[t * 3 + 1] = x1;
    s_xyz[t * 3 + 2] = x2;
    s_scl[t * 3 + 0] = 0.5f * __logf(fabsf(sf0 * sx)) - __logf(fabsf(cvx) + 10.f);
    s_scl[t * 3 + 1] = 0.5f * __logf(fabsf(sf1 * sy)) - __logf(fabsf(cvy) + 10.f);
    s_scl[t * 3 + 2] = 0.5f * __logf(fabsf(sf2 * 10.f)) - __logf(11.f);
    __syncthreads();

    if (t < 192) {
        reinterpret_cast<float4*>(out + n0 * 3)[t] =
            reinterpret_cast<const float4*>(s_xyz)[t];
        reinterpret_cast<float4*>(out + N4 + n0 * 3)[t] =
            reinterpret_cast<const float4*>(s_scl)[t];
    }
}

// ---------------------------------------------------------------------------
// Kernel 3: SH synthesis (R3's validated separable two-stage version).
// 4 blocks/patch, 256 threads; stores perfectly contiguous (16 B/lane).
// ---------------------------------------------------------------------------
__global__ __launch_bounds__(256) void spline_sh(
    const float* __restrict__ sh_dc,    // [P,4,4,1,3]
    const float* __restrict__ sh_rest,  // [P,4,4,15,3]
    const float* __restrict__ b_u,      // [P,32,4]
    const float* __restrict__ b_v,
    float* __restrict__ out)
{
    const int blk = blockIdx.x;
    const int a = blk >> 2, q = blk & 3;
    const int t = threadIdx.x;

    __shared__ float s_sh[16][48];
    __shared__ float s_bu[8][4];
    __shared__ float s_bv[32][4];
    __shared__ float s_tmp[8 * 4 * 52];

    for (int idx = t; idx < 768; idx += 256) {
        const int kl = idx / 48, c = idx - kl * 48;
        s_sh[kl][c] = (c < 3) ? sh_dc[a * 48 + kl * 3 + c]
                              : sh_rest[a * 720 + kl * 45 + (c - 3)];
    }
    if (t < 32)  s_bu[t >> 2][t & 3] = b_u[a * 128 + q * 32 + t];
    if (t < 128) s_bv[t >> 2][t & 3] = b_v[a * 128 + t];
    __syncthreads();

    #pragma unroll
    for (int r = 0; r < 2; ++r) {
        const int e4 = t + r * 256;
        if (e4 < 384) {
            const int i = e4 / 48, rem = e4 - i * 48;
            const int l = rem / 12, cq = rem - l * 12;
            float ax = 0.f, ay = 0.f, az = 0.f, aw = 0.f;
            #pragma unroll
            for (int k = 0; k < 4; ++k) {
                const float w = s_bu[i][k];
                const float4 v = *reinterpret_cast<const float4*>(&s_sh[k * 4 + l][cq * 4]);
                ax += w * v.x; ay += w * v.y; az += w * v.z; aw += w * v.w;
            }
            *reinterpret_cast<float4*>(&s_tmp[i * 208 + l * 52 + cq * 4]) =
                make_float4(ax, ay, az, aw);
        }
    }
    __syncthreads();

    float4* __restrict__ out4 =
        reinterpret_cast<float4*>(out + 11L * NTOT) + (long)a * 12288 + q * 3072;

    #pragma unroll
    for (int k = 0; k < 12; ++k) {
        const unsigned f = t + (k << 8);
        const unsigned p = f / 12u;
        const unsigned c = f - p * 12u;
        const int i = p >> 5;
        const int j = p & 31;

        const float4 bv = *reinterpret_cast<const float4*>(s_bv[j]);
        const float* base = &s_tmp[i * 208 + c * 4];

        const float4 t0 = *reinterpret_cast<const float4*>(base + 0 * 52);
        const float4 t1 = *reinterpret_cast<const float4*>(base + 1 * 52);
        const float4 t2 = *reinterpret_cast<const float4*>(base + 2 * 52);
        const float4 t3 = *reinterpret_cast<const float4*>(base + 3 * 52);

        out4[f] = make_float4(
            bv.x * t0.x + bv.y * t1.x + bv.z * t2.x + bv.w * t3.x,
            bv.x * t0.y + bv.y * t1.y + bv.z * t2.y + bv.w * t3.y,
            bv.x * t0.z + bv.y * t1.z + bv.z * t2.z + bv.w * t3.z,
            bv.x * t0.w + bv.y * t1.w + bv.z * t2.w + bv.w * t3.w);
    }
}

extern "C" void kernel_launch(void* const* d_in, const int* in_sizes, int n_in,
                              void* d_out, int out_size, void* d_ws, size_t ws_size,
                              hipStream_t stream) {
    const float* cp      = (const float*)d_in[0];
    const float* Wt      = (const float*)d_in[1];
    const float* sh_dc   = (const float*)d_in[2];
    const float* sh_rest = (const float*)d_in[3];
    const float* spar    = (const float*)d_in[4];
    const float* opac    = (const float*)d_in[5];
    const float* b_u     = (const float*)d_in[6];
    const float* b_v     = (const float*)d_in[7];
    const float* db_u    = (const float*)d_in[8];
    const float* db_v    = (const float*)d_in[9];
    const float* ddb_u   = (const float*)d_in[10];
    const float* ddb_v   = (const float*)d_in[11];
    float* out = (float*)d_out;
    float* ws  = (float*)d_ws;

    hipLaunchKernelGGL(area_kernel, dim3(NPATCH), dim3(256), 0, stream,
                       cp, Wt, b_u, b_v, db_u, db_v, ws);
    hipLaunchKernelGGL(geom_kernel, dim3(NPATCH * 4), dim3(256), 0, stream,
                       cp, Wt, spar, opac,
                       b_u, b_v, db_u, db_v, ddb_u, ddb_v, ws, out);
    hipLaunchKernelGGL(spline_sh, dim3(NPATCH * 4), dim3(256), 0, stream,
                       sh_dc, sh_rest, b_u, b_v, out);
}

// Round 8
// 131.228 us; speedup vs baseline: 1.1451x; 1.1040x over previous
//
#include <hip/hip_runtime.h>
#include <math.h>

#define NPATCH 2048
#define NPTS 1024
#define NTOT (NPATCH * NPTS)

using f4 = __attribute__((ext_vector_type(4))) float;

__device__ __forceinline__ void nt_store4(float* p, float a, float b, float c, float d) {
    f4 v = {a, b, c, d};
    __builtin_nontemporal_store(v, reinterpret_cast<f4*>(p));
}
__device__ __forceinline__ void nt_copy4(float* dst, const float* src) {
    f4 v = *reinterpret_cast<const f4*>(src);
    __builtin_nontemporal_store(v, reinterpret_cast<f4*>(dst));
}

// ---------------------------------------------------------------------------
// Kernel 1: per-patch area sum -> ws[a]. (validated R4, unchanged)
// ---------------------------------------------------------------------------
__global__ __launch_bounds__(256) void area_kernel(
    const float* __restrict__ cp,       // [P,4,4,3]
    const float* __restrict__ Wt,       // [P,4,4]
    const float* __restrict__ b_u,      // [P,32,4]
    const float* __restrict__ b_v,
    const float* __restrict__ db_u,
    const float* __restrict__ db_v,
    float* __restrict__ ws)
{
    const int a = blockIdx.x;
    const int tid = threadIdx.x;

    __shared__ float s_W[16];
    __shared__ float s_wcp[16][3];
    __shared__ float s_bu[32][4];
    __shared__ float s_bv[32][4];
    __shared__ float s_dbu[32][4];
    __shared__ float s_dbv[32][4];
    __shared__ float s_red[4];

    if (tid < 16) s_W[tid] = Wt[a * 16 + tid];
    if (tid < 48) {
        const int kl = tid / 3, m = tid - kl * 3;
        s_wcp[kl][m] = cp[a * 48 + tid] * Wt[a * 16 + kl];
    }
    if (tid < 128) {
        s_bu [tid >> 2][tid & 3] = b_u [a * 128 + tid];
        s_bv [tid >> 2][tid & 3] = b_v [a * 128 + tid];
        s_dbu[tid >> 2][tid & 3] = db_u[a * 128 + tid];
        s_dbv[tid >> 2][tid & 3] = db_v[a * 128 + tid];
    }
    __syncthreads();

    float acc = 0.f;
    #pragma unroll
    for (int s2 = 0; s2 < 4; ++s2) {
        const int pp = tid + s2 * 256;
        const int i = pp >> 5, j = pp & 31;
        float den = 0.f;
        float du0 = 0, du1 = 0, du2 = 0, dv0 = 0, dv1 = 0, dv2 = 0;
        #pragma unroll
        for (int kl = 0; kl < 16; ++kl) {
            const int k = kl >> 2, l = kl & 3;
            const float bb  = s_bu[i][k] * s_bv[j][l];
            const float wdu = s_dbu[i][k] * s_bv[j][l];
            const float wdv = s_bu[i][k] * s_dbv[j][l];
            den += bb * s_W[kl];
            const float c0 = s_wcp[kl][0], c1 = s_wcp[kl][1], c2 = s_wcp[kl][2];
            du0 += wdu * c0; du1 += wdu * c1; du2 += wdu * c2;
            dv0 += wdv * c0; dv1 += wdv * c1; dv2 += wdv * c2;
        }
        if (den == 0.f) den = 1.f;
        const float inv = 1.0f / den;
        const float cx = du1 * dv2 - du2 * dv1;
        const float cy = du2 * dv0 - du0 * dv2;
        const float cz = du0 * dv1 - du1 * dv0;
        acc += sqrtf(cx * cx + cy * cy + cz * cz) * inv * inv;
    }

    #pragma unroll
    for (int off = 32; off > 0; off >>= 1)
        acc += __shfl_down(acc, off, 64);
    if ((tid & 63) == 0) s_red[tid >> 6] = acc;
    __syncthreads();
    if (tid == 0) ws[a] = s_red[0] + s_red[1] + s_red[2] + s_red[3];
}

// ---------------------------------------------------------------------------
// Kernel 2: geometry quarter-patch, 1 pt/thread. All output via NT stores.
// ---------------------------------------------------------------------------
__global__ __launch_bounds__(256) void geom_kernel(
    const float* __restrict__ cp,       // [P,4,4,3]
    const float* __restrict__ Wt,       // [P,4,4]
    const float* __restrict__ spar,     // [P,2]
    const float* __restrict__ opac,     // [N,1]
    const float* __restrict__ b_u,      // [P,32,4]
    const float* __restrict__ b_v,
    const float* __restrict__ db_u,
    const float* __restrict__ db_v,
    const float* __restrict__ ddb_u,
    const float* __restrict__ ddb_v,
    const float* __restrict__ ws,
    float* __restrict__ out)
{
    const int blk = blockIdx.x;
    const int a = blk >> 2, q = blk & 3;
    const int t = threadIdx.x;

    __shared__ float g_W[16];
    __shared__ float g_wcp[16][3];
    __shared__ float g_bu[8][4];
    __shared__ float g_dbu[8][4];
    __shared__ float g_ddbu[8][4];
    __shared__ float g_bv[32][4];
    __shared__ float g_dbv[32][4];
    __shared__ float g_ddbv[32][4];
    __shared__ __align__(16) float s_xyz[768];
    __shared__ __align__(16) float s_scl[768];

    if (t < 16) g_W[t] = Wt[a * 16 + t];
    if (t < 48) {
        const int kl = t / 3, m = t - kl * 3;
        g_wcp[kl][m] = cp[a * 48 + t] * Wt[a * 16 + kl];
    }
    if (t < 32) {
        g_bu  [t >> 2][t & 3] = b_u  [a * 128 + q * 32 + t];
        g_dbu [t >> 2][t & 3] = db_u [a * 128 + q * 32 + t];
        g_ddbu[t >> 2][t & 3] = ddb_u[a * 128 + q * 32 + t];
    }
    if (t < 128) {
        g_bv  [t >> 2][t & 3] = b_v  [a * 128 + t];
        g_dbv [t >> 2][t & 3] = db_v [a * 128 + t];
        g_ddbv[t >> 2][t & 3] = ddb_v[a * 128 + t];
    }
    __syncthreads();

    const long N3 = 3L * NTOT, N4 = 4L * NTOT, N7 = 7L * NTOT;
    const long n0 = (long)a * NPTS + q * 256;
    const long n  = n0 + t;

    const int i = t >> 5, j = t & 31;
    float bu[4], bv[4], dbu_[4], dbv_[4], ddbu_[4], ddbv_[4];
    #pragma unroll
    for (int k = 0; k < 4; ++k) {
        bu[k]    = g_bu[i][k];    bv[k]    = g_bv[j][k];
        dbu_[k]  = g_dbu[i][k];   dbv_[k]  = g_dbv[j][k];
        ddbu_[k] = g_ddbu[i][k];  ddbv_[k] = g_ddbv[j][k];
    }

    float den = 0.f;
    float x0 = 0, x1 = 0, x2 = 0;
    float du0 = 0, du1 = 0, du2 = 0, dv0 = 0, dv1 = 0, dv2 = 0;
    float eu0 = 0, eu1 = 0, eu2 = 0, ev0 = 0, ev1 = 0, ev2 = 0;
    #pragma unroll
    for (int kl = 0; kl < 16; ++kl) {
        const int k = kl >> 2, l = kl & 3;
        const float bb  = bu[k] * bv[l];
        const float wdu = dbu_[k] * bv[l];
        const float wdv = bu[k] * dbv_[l];
        const float weu = ddbu_[k] * bv[l];
        const float wev = bu[k] * ddbv_[l];
        den += bb * g_W[kl];
        const float c0 = g_wcp[kl][0], c1 = g_wcp[kl][1], c2 = g_wcp[kl][2];
        x0  += bb  * c0; x1  += bb  * c1; x2  += bb  * c2;
        du0 += wdu * c0; du1 += wdu * c1; du2 += wdu * c2;
        dv0 += wdv * c0; dv1 += wdv * c1; dv2 += wdv * c2;
        eu0 += weu * c0; eu1 += weu * c1; eu2 += weu * c2;
        ev0 += wev * c0; ev1 += wev * c1; ev2 += wev * c2;
    }
    if (den == 0.f) den = 1.f;
    const float inv = 1.0f / den;
    x0 *= inv; x1 *= inv; x2 *= inv;
    du0 *= inv; du1 *= inv; du2 *= inv;
    dv0 *= inv; dv1 *= inv; dv2 *= inv;
    eu0 *= inv; eu1 *= inv; eu2 *= inv;
    ev0 *= inv; ev1 *= inv; ev2 *= inv;

    const float cx = du1 * dv2 - du2 * dv1;
    const float cy = du2 * dv0 - du0 * dv2;
    const float cz = du0 * dv1 - du1 * dv0;

    float l1 = fabsf(cx) + fabsf(cy) + fabsf(cz);
    l1 = fmaxf(l1, 1e-12f);
    float nx = cx / l1, ny = cy / l1, nz = cz / l1;
    float l2 = sqrtf(nx * nx + ny * ny + nz * nz);
    l2 = fmaxf(l2, 1e-12f);
    nx /= l2; ny /= l2; nz /= l2;
    const float qw = 1.f + nz, qx = -ny, qy = nx;
    float qn = sqrtf(qw * qw + qx * qx + qy * qy);
    qn = fmaxf(qn, 1e-12f);
    const float rqn = 1.0f / qn;

    nt_store4(out + N7 + n * 4, qw * rqn, qx * rqn, qy * rqn, 0.f);

    if (t < 64)
        nt_copy4(out + N3 + n0 + 4 * t, opac + n0 + 4 * t);

    const float sx  = du0 * du0 + du1 * du1 + du2 * du2 + 10.f;
    const float sy  = dv0 * dv0 + dv1 * dv1 + dv2 * dv2 + 10.f;
    const float cvx = eu0 + eu1 + eu2;
    const float cvy = ev0 + ev1 + ev2;

    const float factor = ws[a] * (1.0f / 1024.0f) * (1.0f / 1024.0f);
    const float sp0 = spar[a * 2 + 0], sp1 = spar[a * 2 + 1];
    const float sf0 = factor * sp0;
    const float sf1 = factor * sp1;
    const float sf2 = factor * 1e-16f;

    s_xyz[t * 3 + 0] = x0;
    s_xyz[t * 3 + 1] = x1;
    s_xyz[t * 3 + 2] = x2;
    s_scl[t * 3 + 0] = 0.5f * __logf(fabsf(sf0 * sx)) - __logf(fabsf(cvx) + 10.f);
    s_scl[t * 3 + 1] = 0.5f * __logf(fabsf(sf1 * sy)) - __logf(fabsf(cvy) + 10.f);
    s_scl[t * 3 + 2] = 0.5f * __logf(fabsf(sf2 * 10.f)) - __logf(11.f);
    __syncthreads();

    if (t < 192) {
        nt_copy4(out + n0 * 3 + 4 * t, s_xyz + 4 * t);
        nt_copy4(out + N4 + n0 * 3 + 4 * t, s_scl + 4 * t);
    }
}

// ---------------------------------------------------------------------------
// Kernel 3: SH synthesis (R3 separable two-stage), NT stores.
// ---------------------------------------------------------------------------
__global__ __launch_bounds__(256) void spline_sh(
    const float* __restrict__ sh_dc,    // [P,4,4,1,3]
    const float* __restrict__ sh_rest,  // [P,4,4,15,3]
    const float* __restrict__ b_u,      // [P,32,4]
    const float* __restrict__ b_v,
    float* __restrict__ out)
{
    const int blk = blockIdx.x;
    const int a = blk >> 2, q = blk & 3;
    const int t = threadIdx.x;

    __shared__ float s_sh[16][48];
    __shared__ float s_bu[8][4];
    __shared__ float s_bv[32][4];
    __shared__ float s_tmp[8 * 4 * 52];

    for (int idx = t; idx < 768; idx += 256) {
        const int kl = idx / 48, c = idx - kl * 48;
        s_sh[kl][c] = (c < 3) ? sh_dc[a * 48 + kl * 3 + c]
                              : sh_rest[a * 720 + kl * 45 + (c - 3)];
    }
    if (t < 32)  s_bu[t >> 2][t & 3] = b_u[a * 128 + q * 32 + t];
    if (t < 128) s_bv[t >> 2][t & 3] = b_v[a * 128 + t];
    __syncthreads();

    #pragma unroll
    for (int r = 0; r < 2; ++r) {
        const int e4 = t + r * 256;
        if (e4 < 384) {
            const int i = e4 / 48, rem = e4 - i * 48;
            const int l = rem / 12, cq = rem - l * 12;
            float ax = 0.f, ay = 0.f, az = 0.f, aw = 0.f;
            #pragma unroll
            for (int k = 0; k < 4; ++k) {
                const float w = s_bu[i][k];
                const float4 v = *reinterpret_cast<const float4*>(&s_sh[k * 4 + l][cq * 4]);
                ax += w * v.x; ay += w * v.y; az += w * v.z; aw += w * v.w;
            }
            *reinterpret_cast<float4*>(&s_tmp[i * 208 + l * 52 + cq * 4]) =
                make_float4(ax, ay, az, aw);
        }
    }
    __syncthreads();

    float* __restrict__ outp =
        out + 11L * NTOT + ((long)a * 12288 + q * 3072) * 4;

    #pragma unroll
    for (int k = 0; k < 12; ++k) {
        const unsigned f = t + (k << 8);
        const unsigned p = f / 12u;
        const unsigned c = f - p * 12u;
        const int i = p >> 5;
        const int j = p & 31;

        const float4 bv = *reinterpret_cast<const float4*>(s_bv[j]);
        const float* base = &s_tmp[i * 208 + c * 4];

        const float4 t0 = *reinterpret_cast<const float4*>(base + 0 * 52);
        const float4 t1 = *reinterpret_cast<const float4*>(base + 1 * 52);
        const float4 t2 = *reinterpret_cast<const float4*>(base + 2 * 52);
        const float4 t3 = *reinterpret_cast<const float4*>(base + 3 * 52);

        nt_store4(outp + f * 4,
            bv.x * t0.x + bv.y * t1.x + bv.z * t2.x + bv.w * t3.x,
            bv.x * t0.y + bv.y * t1.y + bv.z * t2.y + bv.w * t3.y,
            bv.x * t0.z + bv.y * t1.z + bv.z * t2.z + bv.w * t3.z,
            bv.x * t0.w + bv.y * t1.w + bv.z * t2.w + bv.w * t3.w);
    }
}

extern "C" void kernel_launch(void* const* d_in, const int* in_sizes, int n_in,
                              void* d_out, int out_size, void* d_ws, size_t ws_size,
                              hipStream_t stream) {
    const float* cp      = (const float*)d_in[0];
    const float* Wt      = (const float*)d_in[1];
    const float* sh_dc   = (const float*)d_in[2];
    const float* sh_rest = (const float*)d_in[3];
    const float* spar    = (const float*)d_in[4];
    const float* opac    = (const float*)d_in[5];
    const float* b_u     = (const float*)d_in[6];
    const float* b_v     = (const float*)d_in[7];
    const float* db_u    = (const float*)d_in[8];
    const float* db_v    = (const float*)d_in[9];
    const float* ddb_u   = (const float*)d_in[10];
    const float* ddb_v   = (const float*)d_in[11];
    float* out = (float*)d_out;
    float* ws  = (float*)d_ws;

    hipLaunchKernelGGL(area_kernel, dim3(NPATCH), dim3(256), 0, stream,
                       cp, Wt, b_u, b_v, db_u, db_v, ws);
    hipLaunchKernelGGL(geom_kernel, dim3(NPATCH * 4), dim3(256), 0, stream,
                       cp, Wt, spar, opac,
                       b_u, b_v, db_u, db_v, ddb_u, ddb_v, ws, out);
    hipLaunchKernelGGL(spline_sh, dim3(NPATCH * 4), dim3(256), 0, stream,
                       sh_dc, sh_rest, b_u, b_v, out);
}

// Round 9
// 114.042 us; speedup vs baseline: 1.3177x; 1.1507x over previous
//
#include <hip/hip_runtime.h>
#include <math.h>

#define NPATCH 2048
#define NPTS 1024
#define NTOT (NPATCH * NPTS)

using f4 = __attribute__((ext_vector_type(4))) float;

__device__ __forceinline__ void nt_store4(float* p, float a, float b, float c, float d) {
    f4 v = {a, b, c, d};
    __builtin_nontemporal_store(v, reinterpret_cast<f4*>(p));
}
__device__ __forceinline__ void nt_copy4(float* dst, const float* src) {
    f4 v = *reinterpret_cast<const f4*>(src);
    __builtin_nontemporal_store(v, reinterpret_cast<f4*>(dst));
}

// ---------------------------------------------------------------------------
// Kernel 1: per-patch area sum -> ws[a].  Separable stage-1:
//   tB[i][l][m] = sum_k bu[i][k]*wcp[k4+l][m]; tD likewise with dbu;
//   wB[i][l]    = sum_k bu[i][k]*W[k4+l].
// Stage-2 per point: 28 FMA (vs 112) + cross + sqrt.
// ---------------------------------------------------------------------------
__global__ __launch_bounds__(256) void area_kernel(
    const float* __restrict__ cp,       // [P,4,4,3]
    const float* __restrict__ Wt,       // [P,4,4]
    const float* __restrict__ b_u,      // [P,32,4]
    const float* __restrict__ b_v,
    const float* __restrict__ db_u,
    const float* __restrict__ db_v,
    float* __restrict__ ws)
{
    const int a = blockIdx.x;
    const int t = threadIdx.x;

    __shared__ float s_W[16];
    __shared__ __align__(16) float s_wcp4[16][4];
    __shared__ __align__(16) float s_bu[32][4];
    __shared__ __align__(16) float s_bv[32][4];
    __shared__ __align__(16) float s_dbu[32][4];
    __shared__ __align__(16) float s_dbv[32][4];
    __shared__ __align__(16) float s_tB[128][4];   // [i*4+l][m]
    __shared__ __align__(16) float s_tD[128][4];
    __shared__ __align__(16) float s_wB[128];      // [i*4+l]
    __shared__ float s_red[4];

    if (t < 16) {
        const float w = Wt[a * 16 + t];
        s_W[t] = w;
        s_wcp4[t][0] = cp[a * 48 + t * 3 + 0] * w;
        s_wcp4[t][1] = cp[a * 48 + t * 3 + 1] * w;
        s_wcp4[t][2] = cp[a * 48 + t * 3 + 2] * w;
        s_wcp4[t][3] = 0.f;
    }
    if (t < 128) {
        s_bu [t >> 2][t & 3] = b_u [a * 128 + t];
        s_bv [t >> 2][t & 3] = b_v [a * 128 + t];
        s_dbu[t >> 2][t & 3] = db_u[a * 128 + t];
        s_dbv[t >> 2][t & 3] = db_v[a * 128 + t];
    }
    __syncthreads();

    // stage 1
    if (t < 128) {
        const int i = t >> 2, l = t & 3;
        f4 acc = {0.f, 0.f, 0.f, 0.f};
        float wa = 0.f;
        #pragma unroll
        for (int k = 0; k < 4; ++k) {
            const float b = s_bu[i][k];
            const f4 v = *reinterpret_cast<const f4*>(s_wcp4[k * 4 + l]);
            acc += b * v;
            wa  += b * s_W[k * 4 + l];
        }
        *reinterpret_cast<f4*>(s_tB[t]) = acc;
        s_wB[t] = wa;
    } else {
        const int tt = t - 128;
        const int i = tt >> 2, l = tt & 3;
        f4 acc = {0.f, 0.f, 0.f, 0.f};
        #pragma unroll
        for (int k = 0; k < 4; ++k)
            acc += s_dbu[i][k] * *reinterpret_cast<const f4*>(s_wcp4[k * 4 + l]);
        *reinterpret_cast<f4*>(s_tD[tt]) = acc;
    }
    __syncthreads();

    // stage 2: 4 points/thread; j fixed per thread, i varies
    const int j = t & 31;
    const f4 bv  = *reinterpret_cast<const f4*>(s_bv[j]);
    const f4 dbv = *reinterpret_cast<const f4*>(s_dbv[j]);

    float acc = 0.f;
    #pragma unroll
    for (int s2 = 0; s2 < 4; ++s2) {
        const int i = (t >> 5) + 8 * s2;
        const f4 tb0 = *reinterpret_cast<const f4*>(s_tB[i * 4 + 0]);
        const f4 tb1 = *reinterpret_cast<const f4*>(s_tB[i * 4 + 1]);
        const f4 tb2 = *reinterpret_cast<const f4*>(s_tB[i * 4 + 2]);
        const f4 tb3 = *reinterpret_cast<const f4*>(s_tB[i * 4 + 3]);
        const f4 td0 = *reinterpret_cast<const f4*>(s_tD[i * 4 + 0]);
        const f4 td1 = *reinterpret_cast<const f4*>(s_tD[i * 4 + 1]);
        const f4 td2 = *reinterpret_cast<const f4*>(s_tD[i * 4 + 2]);
        const f4 td3 = *reinterpret_cast<const f4*>(s_tD[i * 4 + 3]);
        const f4 wb  = *(reinterpret_cast<const f4*>(s_wB) + i);

        float den = bv.x * wb.x + bv.y * wb.y + bv.z * wb.z + bv.w * wb.w;
        if (den == 0.f) den = 1.f;
        const float inv = 1.0f / den;

        const f4 du = bv.x  * td0 + bv.y  * td1 + bv.z  * td2 + bv.w  * td3;
        const f4 dv = dbv.x * tb0 + dbv.y * tb1 + dbv.z * tb2 + dbv.w * tb3;

        const float cx = du.y * dv.z - du.z * dv.y;
        const float cy = du.z * dv.x - du.x * dv.z;
        const float cz = du.x * dv.y - du.y * dv.x;
        acc += sqrtf(cx * cx + cy * cy + cz * cz) * inv * inv;
    }

    #pragma unroll
    for (int off = 32; off > 0; off >>= 1)
        acc += __shfl_down(acc, off, 64);
    if ((t & 63) == 0) s_red[t >> 6] = acc;
    __syncthreads();
    if (t == 0) ws[a] = s_red[0] + s_red[1] + s_red[2] + s_red[3];
}

// ---------------------------------------------------------------------------
// Kernel 2: geometry quarter-patch, 1 pt/thread, separable stage-1
// (tB/tD/tE/wB for this block's 8 u-rows). All output via NT stores.
// ---------------------------------------------------------------------------
__global__ __launch_bounds__(256) void geom_kernel(
    const float* __restrict__ cp,       // [P,4,4,3]
    const float* __restrict__ Wt,       // [P,4,4]
    const float* __restrict__ spar,     // [P,2]
    const float* __restrict__ opac,     // [N,1]
    const float* __restrict__ b_u,      // [P,32,4]
    const float* __restrict__ b_v,
    const float* __restrict__ db_u,
    const float* __restrict__ db_v,
    const float* __restrict__ ddb_u,
    const float* __restrict__ ddb_v,
    const float* __restrict__ ws,
    float* __restrict__ out)
{
    const int blk = blockIdx.x;
    const int a = blk >> 2, q = blk & 3;
    const int t = threadIdx.x;

    __shared__ float s_W[16];
    __shared__ __align__(16) float s_wcp4[16][4];
    __shared__ __align__(16) float g_bu[8][4];
    __shared__ __align__(16) float g_dbu[8][4];
    __shared__ __align__(16) float g_ddbu[8][4];
    __shared__ __align__(16) float g_bv[32][4];
    __shared__ __align__(16) float g_dbv[32][4];
    __shared__ __align__(16) float g_ddbv[32][4];
    __shared__ __align__(16) float s_tB[32][4];
    __shared__ __align__(16) float s_tD[32][4];
    __shared__ __align__(16) float s_tE[32][4];
    __shared__ __align__(16) float s_wB[32];
    __shared__ __align__(16) float s_xyz[768];
    __shared__ __align__(16) float s_scl[768];

    if (t < 16) {
        const float w = Wt[a * 16 + t];
        s_W[t] = w;
        s_wcp4[t][0] = cp[a * 48 + t * 3 + 0] * w;
        s_wcp4[t][1] = cp[a * 48 + t * 3 + 1] * w;
        s_wcp4[t][2] = cp[a * 48 + t * 3 + 2] * w;
        s_wcp4[t][3] = 0.f;
    }
    if (t < 32) {
        g_bu  [t >> 2][t & 3] = b_u  [a * 128 + q * 32 + t];
        g_dbu [t >> 2][t & 3] = db_u [a * 128 + q * 32 + t];
        g_ddbu[t >> 2][t & 3] = ddb_u[a * 128 + q * 32 + t];
    }
    if (t < 128) {
        g_bv  [t >> 2][t & 3] = b_v  [a * 128 + t];
        g_dbv [t >> 2][t & 3] = db_v [a * 128 + t];
        g_ddbv[t >> 2][t & 3] = ddb_v[a * 128 + t];
    }
    __syncthreads();

    // stage 1: 8 u-rows
    if (t < 32) {
        const int i = t >> 2, l = t & 3;
        f4 acc = {0.f, 0.f, 0.f, 0.f};
        float wa = 0.f;
        #pragma unroll
        for (int k = 0; k < 4; ++k) {
            const float b = g_bu[i][k];
            acc += b * *reinterpret_cast<const f4*>(s_wcp4[k * 4 + l]);
            wa  += b * s_W[k * 4 + l];
        }
        *reinterpret_cast<f4*>(s_tB[t]) = acc;
        s_wB[t] = wa;
    } else if (t < 64) {
        const int tt = t - 32, i = tt >> 2, l = tt & 3;
        f4 acc = {0.f, 0.f, 0.f, 0.f};
        #pragma unroll
        for (int k = 0; k < 4; ++k)
            acc += g_dbu[i][k] * *reinterpret_cast<const f4*>(s_wcp4[k * 4 + l]);
        *reinterpret_cast<f4*>(s_tD[tt]) = acc;
    } else if (t < 96) {
        const int tt = t - 64, i = tt >> 2, l = tt & 3;
        f4 acc = {0.f, 0.f, 0.f, 0.f};
        #pragma unroll
        for (int k = 0; k < 4; ++k)
            acc += g_ddbu[i][k] * *reinterpret_cast<const f4*>(s_wcp4[k * 4 + l]);
        *reinterpret_cast<f4*>(s_tE[tt]) = acc;
    }
    __syncthreads();

    const long N3 = 3L * NTOT, N4 = 4L * NTOT, N7 = 7L * NTOT;
    const long n0 = (long)a * NPTS + q * 256;
    const long n  = n0 + t;

    // stage 2
    const int i = t >> 5, j = t & 31;
    const f4 bv   = *reinterpret_cast<const f4*>(g_bv[j]);
    const f4 dbv  = *reinterpret_cast<const f4*>(g_dbv[j]);
    const f4 ddbv = *reinterpret_cast<const f4*>(g_ddbv[j]);

    const f4 tb0 = *reinterpret_cast<const f4*>(s_tB[i * 4 + 0]);
    const f4 tb1 = *reinterpret_cast<const f4*>(s_tB[i * 4 + 1]);
    const f4 tb2 = *reinterpret_cast<const f4*>(s_tB[i * 4 + 2]);
    const f4 tb3 = *reinterpret_cast<const f4*>(s_tB[i * 4 + 3]);
    const f4 td0 = *reinterpret_cast<const f4*>(s_tD[i * 4 + 0]);
    const f4 td1 = *reinterpret_cast<const f4*>(s_tD[i * 4 + 1]);
    const f4 td2 = *reinterpret_cast<const f4*>(s_tD[i * 4 + 2]);
    const f4 td3 = *reinterpret_cast<const f4*>(s_tD[i * 4 + 3]);
    const f4 te0 = *reinterpret_cast<const f4*>(s_tE[i * 4 + 0]);
    const f4 te1 = *reinterpret_cast<const f4*>(s_tE[i * 4 + 1]);
    const f4 te2 = *reinterpret_cast<const f4*>(s_tE[i * 4 + 2]);
    const f4 te3 = *reinterpret_cast<const f4*>(s_tE[i * 4 + 3]);
    const f4 wb  = *(reinterpret_cast<const f4*>(s_wB) + i);

    float den = bv.x * wb.x + bv.y * wb.y + bv.z * wb.z + bv.w * wb.w;
    if (den == 0.f) den = 1.f;
    const float inv = 1.0f / den;

    const f4 xyz = bv.x  * tb0 + bv.y  * tb1 + bv.z  * tb2 + bv.w  * tb3;
    const f4 du  = bv.x  * td0 + bv.y  * td1 + bv.z  * td2 + bv.w  * td3;
    const f4 dv  = dbv.x * tb0 + dbv.y * tb1 + dbv.z * tb2 + dbv.w * tb3;
    const f4 eu  = bv.x  * te0 + bv.y  * te1 + bv.z  * te2 + bv.w  * te3;
    const f4 ev  = ddbv.x* tb0 + ddbv.y* tb1 + ddbv.z* tb2 + ddbv.w* tb3;

    const float x0 = xyz.x * inv, x1 = xyz.y * inv, x2 = xyz.z * inv;
    const float du0 = du.x * inv, du1 = du.y * inv, du2 = du.z * inv;
    const float dv0 = dv.x * inv, dv1 = dv.y * inv, dv2 = dv.z * inv;

    const float cx = du1 * dv2 - du2 * dv1;
    const float cy = du2 * dv0 - du0 * dv2;
    const float cz = du0 * dv1 - du1 * dv0;

    float l1 = fabsf(cx) + fabsf(cy) + fabsf(cz);
    l1 = fmaxf(l1, 1e-12f);
    float nx = cx / l1, ny = cy / l1, nz = cz / l1;
    float l2 = sqrtf(nx * nx + ny * ny + nz * nz);
    l2 = fmaxf(l2, 1e-12f);
    nx /= l2; ny /= l2; nz /= l2;
    const float qw = 1.f + nz, qx = -ny, qy = nx;
    float qn = sqrtf(qw * qw + qx * qx + qy * qy);
    qn = fmaxf(qn, 1e-12f);
    const float rqn = 1.0f / qn;

    nt_store4(out + N7 + n * 4, qw * rqn, qx * rqn, qy * rqn, 0.f);

    if (t < 64)
        nt_copy4(out + N3 + n0 + 4 * t, opac + n0 + 4 * t);

    const float sx  = du0 * du0 + du1 * du1 + du2 * du2 + 10.f;
    const float sy  = dv0 * dv0 + dv1 * dv1 + dv2 * dv2 + 10.f;
    const float cvx = (eu.x + eu.y + eu.z) * inv;
    const float cvy = (ev.x + ev.y + ev.z) * inv;

    const float factor = ws[a] * (1.0f / 1024.0f) * (1.0f / 1024.0f);
    const float sp0 = spar[a * 2 + 0], sp1 = spar[a * 2 + 1];
    const float sf0 = factor * sp0;
    const float sf1 = factor * sp1;
    const float sf2 = factor * 1e-16f;

    s_xyz[t * 3 + 0] = x0;
    s_xyz[t * 3 + 1] = x1;
    s_xyz[t * 3 + 2] = x2;
    s_scl[t * 3 + 0] = 0.5f * __logf(fabsf(sf0 * sx)) - __logf(fabsf(cvx) + 10.f);
    s_scl[t * 3 + 1] = 0.5f * __logf(fabsf(sf1 * sy)) - __logf(fabsf(cvy) + 10.f);
    s_scl[t * 3 + 2] = 0.5f * __logf(fabsf(sf2 * 10.f)) - __logf(11.f);
    __syncthreads();

    if (t < 192) {
        nt_copy4(out + n0 * 3 + 4 * t, s_xyz + 4 * t);
        nt_copy4(out + N4 + n0 * 3 + 4 * t, s_scl + 4 * t);
    }
}

// ---------------------------------------------------------------------------
// Kernel 3: SH synthesis (R3 separable two-stage), NT stores. (R8 verbatim)
// ---------------------------------------------------------------------------
__global__ __launch_bounds__(256) void spline_sh(
    const float* __restrict__ sh_dc,    // [P,4,4,1,3]
    const float* __restrict__ sh_rest,  // [P,4,4,15,3]
    const float* __restrict__ b_u,      // [P,32,4]
    const float* __restrict__ b_v,
    float* __restrict__ out)
{
    const int blk = blockIdx.x;
    const int a = blk >> 2, q = blk & 3;
    const int t = threadIdx.x;

    __shared__ float s_sh[16][48];
    __shared__ float s_bu[8][4];
    __shared__ float s_bv[32][4];
    __shared__ float s_tmp[8 * 4 * 52];

    for (int idx = t; idx < 768; idx += 256) {
        const int kl = idx / 48, c = idx - kl * 48;
        s_sh[kl][c] = (c < 3) ? sh_dc[a * 48 + kl * 3 + c]
                              : sh_rest[a * 720 + kl * 45 + (c - 3)];
    }
    if (t < 32)  s_bu[t >> 2][t & 3] = b_u[a * 128 + q * 32 + t];
    if (t < 128) s_bv[t >> 2][t & 3] = b_v[a * 128 + t];
    __syncthreads();

    #pragma unroll
    for (int r = 0; r < 2; ++r) {
        const int e4 = t + r * 256;
        if (e4 < 384) {
            const int i = e4 / 48, rem = e4 - i * 48;
            const int l = rem / 12, cq = rem - l * 12;
            float ax = 0.f, ay = 0.f, az = 0.f, aw = 0.f;
            #pragma unroll
            for (int k = 0; k < 4; ++k) {
                const float w = s_bu[i][k];
                const float4 v = *reinterpret_cast<const float4*>(&s_sh[k * 4 + l][cq * 4]);
                ax += w * v.x; ay += w * v.y; az += w * v.z; aw += w * v.w;
            }
            *reinterpret_cast<float4*>(&s_tmp[i * 208 + l * 52 + cq * 4]) =
                make_float4(ax, ay, az, aw);
        }
    }
    __syncthreads();

    float* __restrict__ outp =
        out + 11L * NTOT + ((long)a * 12288 + q * 3072) * 4;

    #pragma unroll
    for (int k = 0; k < 12; ++k) {
        const unsigned f = t + (k << 8);
        const unsigned p = f / 12u;
        const unsigned c = f - p * 12u;
        const int i = p >> 5;
        const int j = p & 31;

        const float4 bv = *reinterpret_cast<const float4*>(s_bv[j]);
        const float* base = &s_tmp[i * 208 + c * 4];

        const float4 t0 = *reinterpret_cast<const float4*>(base + 0 * 52);
        const float4 t1 = *reinterpret_cast<const float4*>(base + 1 * 52);
        const float4 t2 = *reinterpret_cast<const float4*>(base + 2 * 52);
        const float4 t3 = *reinterpret_cast<const float4*>(base + 3 * 52);

        nt_store4(outp + f * 4,
            bv.x * t0.x + bv.y * t1.x + bv.z * t2.x + bv.w * t3.x,
            bv.x * t0.y + bv.y * t1.y + bv.z * t2.y + bv.w * t3.y,
            bv.x * t0.z + bv.y * t1.z + bv.z * t2.z + bv.w * t3.z,
            bv.x * t0.w + bv.y * t1.w + bv.z * t2.w + bv.w * t3.w);
    }
}

extern "C" void kernel_launch(void* const* d_in, const int* in_sizes, int n_in,
                              void* d_out, int out_size, void* d_ws, size_t ws_size,
                              hipStream_t stream) {
    const float* cp      = (const float*)d_in[0];
    const float* Wt      = (const float*)d_in[1];
    const float* sh_dc   = (const float*)d_in[2];
    const float* sh_rest = (const float*)d_in[3];
    const float* spar    = (const float*)d_in[4];
    const float* opac    = (const float*)d_in[5];
    const float* b_u     = (const float*)d_in[6];
    const float* b_v     = (const float*)d_in[7];
    const float* db_u    = (const float*)d_in[8];
    const float* db_v    = (const float*)d_in[9];
    const float* ddb_u   = (const float*)d_in[10];
    const float* ddb_v   = (const float*)d_in[11];
    float* out = (float*)d_out;
    float* ws  = (float*)d_ws;

    hipLaunchKernelGGL(area_kernel, dim3(NPATCH), dim3(256), 0, stream,
                       cp, Wt, b_u, b_v, db_u, db_v, ws);
    hipLaunchKernelGGL(geom_kernel, dim3(NPATCH * 4), dim3(256), 0, stream,
                       cp, Wt, spar, opac,
                       b_u, b_v, db_u, db_v, ddb_u, ddb_v, ws, out);
    hipLaunchKernelGGL(spline_sh, dim3(NPATCH * 4), dim3(256), 0, stream,
                       sh_dc, sh_rest, b_u, b_v, out);
}

// Round 10
// 108.426 us; speedup vs baseline: 1.3859x; 1.0518x over previous
//
#include <hip/hip_runtime.h>
#include <math.h>

#define NPATCH 2048
#define NPTS 1024
#define NTOT (NPATCH * NPTS)

using f4 = __attribute__((ext_vector_type(4))) float;

__device__ __forceinline__ void nt_store4(float* p, float a, float b, float c, float d) {
    f4 v = {a, b, c, d};
    __builtin_nontemporal_store(v, reinterpret_cast<f4*>(p));
}
__device__ __forceinline__ void nt_copy4(float* dst, const float* src) {
    f4 v = *reinterpret_cast<const f4*>(src);
    __builtin_nontemporal_store(v, reinterpret_cast<f4*>(dst));
}

// ---------------------------------------------------------------------------
// Kernel 1: per-patch area sum -> ws[a]. (R9 validated, unchanged)
// ---------------------------------------------------------------------------
__global__ __launch_bounds__(256) void area_kernel(
    const float* __restrict__ cp,       // [P,4,4,3]
    const float* __restrict__ Wt,       // [P,4,4]
    const float* __restrict__ b_u,      // [P,32,4]
    const float* __restrict__ b_v,
    const float* __restrict__ db_u,
    const float* __restrict__ db_v,
    float* __restrict__ ws)
{
    const int a = blockIdx.x;
    const int t = threadIdx.x;

    __shared__ float s_W[16];
    __shared__ __align__(16) float s_wcp4[16][4];
    __shared__ __align__(16) float s_bu[32][4];
    __shared__ __align__(16) float s_bv[32][4];
    __shared__ __align__(16) float s_dbu[32][4];
    __shared__ __align__(16) float s_dbv[32][4];
    __shared__ __align__(16) float s_tB[128][4];   // [i*4+l][m]
    __shared__ __align__(16) float s_tD[128][4];
    __shared__ __align__(16) float s_wB[128];      // [i*4+l]
    __shared__ float s_red[4];

    if (t < 16) {
        const float w = Wt[a * 16 + t];
        s_W[t] = w;
        s_wcp4[t][0] = cp[a * 48 + t * 3 + 0] * w;
        s_wcp4[t][1] = cp[a * 48 + t * 3 + 1] * w;
        s_wcp4[t][2] = cp[a * 48 + t * 3 + 2] * w;
        s_wcp4[t][3] = 0.f;
    }
    if (t < 128) {
        s_bu [t >> 2][t & 3] = b_u [a * 128 + t];
        s_bv [t >> 2][t & 3] = b_v [a * 128 + t];
        s_dbu[t >> 2][t & 3] = db_u[a * 128 + t];
        s_dbv[t >> 2][t & 3] = db_v[a * 128 + t];
    }
    __syncthreads();

    if (t < 128) {
        const int i = t >> 2, l = t & 3;
        f4 acc = {0.f, 0.f, 0.f, 0.f};
        float wa = 0.f;
        #pragma unroll
        for (int k = 0; k < 4; ++k) {
            const float b = s_bu[i][k];
            acc += b * *reinterpret_cast<const f4*>(s_wcp4[k * 4 + l]);
            wa  += b * s_W[k * 4 + l];
        }
        *reinterpret_cast<f4*>(s_tB[t]) = acc;
        s_wB[t] = wa;
    } else {
        const int tt = t - 128;
        const int i = tt >> 2, l = tt & 3;
        f4 acc = {0.f, 0.f, 0.f, 0.f};
        #pragma unroll
        for (int k = 0; k < 4; ++k)
            acc += s_dbu[i][k] * *reinterpret_cast<const f4*>(s_wcp4[k * 4 + l]);
        *reinterpret_cast<f4*>(s_tD[tt]) = acc;
    }
    __syncthreads();

    const int j = t & 31;
    const f4 bv  = *reinterpret_cast<const f4*>(s_bv[j]);
    const f4 dbv = *reinterpret_cast<const f4*>(s_dbv[j]);

    float acc = 0.f;
    #pragma unroll
    for (int s2 = 0; s2 < 4; ++s2) {
        const int i = (t >> 5) + 8 * s2;
        const f4 tb0 = *reinterpret_cast<const f4*>(s_tB[i * 4 + 0]);
        const f4 tb1 = *reinterpret_cast<const f4*>(s_tB[i * 4 + 1]);
        const f4 tb2 = *reinterpret_cast<const f4*>(s_tB[i * 4 + 2]);
        const f4 tb3 = *reinterpret_cast<const f4*>(s_tB[i * 4 + 3]);
        const f4 td0 = *reinterpret_cast<const f4*>(s_tD[i * 4 + 0]);
        const f4 td1 = *reinterpret_cast<const f4*>(s_tD[i * 4 + 1]);
        const f4 td2 = *reinterpret_cast<const f4*>(s_tD[i * 4 + 2]);
        const f4 td3 = *reinterpret_cast<const f4*>(s_tD[i * 4 + 3]);
        const f4 wb  = *(reinterpret_cast<const f4*>(s_wB) + i);

        float den = bv.x * wb.x + bv.y * wb.y + bv.z * wb.z + bv.w * wb.w;
        if (den == 0.f) den = 1.f;
        const float inv = 1.0f / den;

        const f4 du = bv.x  * td0 + bv.y  * td1 + bv.z  * td2 + bv.w  * td3;
        const f4 dv = dbv.x * tb0 + dbv.y * tb1 + dbv.z * tb2 + dbv.w * tb3;

        const float cx = du.y * dv.z - du.z * dv.y;
        const float cy = du.z * dv.x - du.x * dv.z;
        const float cz = du.x * dv.y - du.y * dv.x;
        acc += sqrtf(cx * cx + cy * cy + cz * cz) * inv * inv;
    }

    #pragma unroll
    for (int off = 32; off > 0; off >>= 1)
        acc += __shfl_down(acc, off, 64);
    if ((t & 63) == 0) s_red[t >> 6] = acc;
    __syncthreads();
    if (t == 0) ws[a] = s_red[0] + s_red[1] + s_red[2] + s_red[3];
}

// ---------------------------------------------------------------------------
// Kernel 2: FUSED quarter-patch — geometry + SH in the same block so geometry
// VALU hides under the SH store drain. 8192 blocks x 256 threads, NT stores.
// ---------------------------------------------------------------------------
__global__ __launch_bounds__(256) void fused_kernel(
    const float* __restrict__ cp,       // [P,4,4,3]
    const float* __restrict__ Wt,       // [P,4,4]
    const float* __restrict__ sh_dc,    // [P,4,4,1,3]
    const float* __restrict__ sh_rest,  // [P,4,4,15,3]
    const float* __restrict__ spar,     // [P,2]
    const float* __restrict__ opac,     // [N,1]
    const float* __restrict__ b_u,      // [P,32,4]
    const float* __restrict__ b_v,
    const float* __restrict__ db_u,
    const float* __restrict__ db_v,
    const float* __restrict__ ddb_u,
    const float* __restrict__ ddb_v,
    const float* __restrict__ ws,
    float* __restrict__ out)
{
    const int blk = blockIdx.x;
    const int a = blk >> 2, q = blk & 3;
    const int t = threadIdx.x;

    __shared__ float s_W[16];
    __shared__ __align__(16) float s_wcp4[16][4];
    __shared__ __align__(16) float g_bu[8][4];
    __shared__ __align__(16) float g_dbu[8][4];
    __shared__ __align__(16) float g_ddbu[8][4];
    __shared__ __align__(16) float g_bv[32][4];
    __shared__ __align__(16) float g_dbv[32][4];
    __shared__ __align__(16) float g_ddbv[32][4];
    __shared__ __align__(16) float s_tB[32][4];
    __shared__ __align__(16) float s_tD[32][4];
    __shared__ __align__(16) float s_tE[32][4];
    __shared__ __align__(16) float s_wB[32];
    __shared__ __align__(16) float s_sh[16][48];
    __shared__ __align__(16) float s_tmp[8 * 208];   // [i][l][cq]: i*208+l*52+cq*4
    __shared__ __align__(16) float s_xyz[768];
    __shared__ __align__(16) float s_scl[768];

    // ---- staging ----
    if (t < 16) {
        const float w = Wt[a * 16 + t];
        s_W[t] = w;
        s_wcp4[t][0] = cp[a * 48 + t * 3 + 0] * w;
        s_wcp4[t][1] = cp[a * 48 + t * 3 + 1] * w;
        s_wcp4[t][2] = cp[a * 48 + t * 3 + 2] * w;
        s_wcp4[t][3] = 0.f;
    }
    if (t < 32) {
        g_bu  [t >> 2][t & 3] = b_u  [a * 128 + q * 32 + t];
        g_dbu [t >> 2][t & 3] = db_u [a * 128 + q * 32 + t];
        g_ddbu[t >> 2][t & 3] = ddb_u[a * 128 + q * 32 + t];
    }
    if (t < 128) {
        g_bv  [t >> 2][t & 3] = b_v  [a * 128 + t];
        g_dbv [t >> 2][t & 3] = db_v [a * 128 + t];
        g_ddbv[t >> 2][t & 3] = ddb_v[a * 128 + t];
    }
    for (int idx = t; idx < 768; idx += 256) {
        const int kl = idx / 48, c = idx - kl * 48;
        s_sh[kl][c] = (c < 3) ? sh_dc[a * 48 + kl * 3 + c]
                              : sh_rest[a * 720 + kl * 45 + (c - 3)];
    }
    __syncthreads();

    // ---- stage 1: geometry (t<96) + SH (all threads, 384 f4 elems) ----
    if (t < 32) {
        const int i = t >> 2, l = t & 3;
        f4 acc = {0.f, 0.f, 0.f, 0.f};
        float wa = 0.f;
        #pragma unroll
        for (int k = 0; k < 4; ++k) {
            const float b = g_bu[i][k];
            acc += b * *reinterpret_cast<const f4*>(s_wcp4[k * 4 + l]);
            wa  += b * s_W[k * 4 + l];
        }
        *reinterpret_cast<f4*>(s_tB[t]) = acc;
        s_wB[t] = wa;
    } else if (t < 64) {
        const int tt = t - 32, i = tt >> 2, l = tt & 3;
        f4 acc = {0.f, 0.f, 0.f, 0.f};
        #pragma unroll
        for (int k = 0; k < 4; ++k)
            acc += g_dbu[i][k] * *reinterpret_cast<const f4*>(s_wcp4[k * 4 + l]);
        *reinterpret_cast<f4*>(s_tD[tt]) = acc;
    } else if (t < 96) {
        const int tt = t - 64, i = tt >> 2, l = tt & 3;
        f4 acc = {0.f, 0.f, 0.f, 0.f};
        #pragma unroll
        for (int k = 0; k < 4; ++k)
            acc += g_ddbu[i][k] * *reinterpret_cast<const f4*>(s_wcp4[k * 4 + l]);
        *reinterpret_cast<f4*>(s_tE[tt]) = acc;
    }
    #pragma unroll
    for (int r = 0; r < 2; ++r) {
        const int e4 = t + r * 256;
        if (e4 < 384) {
            const int i = e4 / 48, rem = e4 - i * 48;
            const int l = rem / 12, cq = rem - l * 12;
            float ax = 0.f, ay = 0.f, az = 0.f, aw = 0.f;
            #pragma unroll
            for (int k = 0; k < 4; ++k) {
                const float w = g_bu[i][k];
                const float4 v = *reinterpret_cast<const float4*>(&s_sh[k * 4 + l][cq * 4]);
                ax += w * v.x; ay += w * v.y; az += w * v.z; aw += w * v.w;
            }
            *reinterpret_cast<float4*>(&s_tmp[i * 208 + l * 52 + cq * 4]) =
                make_float4(ax, ay, az, aw);
        }
    }
    __syncthreads();

    const long N3 = 3L * NTOT, N4 = 4L * NTOT, N7 = 7L * NTOT;
    const long n0 = (long)a * NPTS + q * 256;
    const long n  = n0 + t;

    // ---- geometry stage 2 ----
    {
        const int i = t >> 5, j = t & 31;
        const f4 bv   = *reinterpret_cast<const f4*>(g_bv[j]);
        const f4 dbv  = *reinterpret_cast<const f4*>(g_dbv[j]);
        const f4 ddbv = *reinterpret_cast<const f4*>(g_ddbv[j]);

        const f4 tb0 = *reinterpret_cast<const f4*>(s_tB[i * 4 + 0]);
        const f4 tb1 = *reinterpret_cast<const f4*>(s_tB[i * 4 + 1]);
        const f4 tb2 = *reinterpret_cast<const f4*>(s_tB[i * 4 + 2]);
        const f4 tb3 = *reinterpret_cast<const f4*>(s_tB[i * 4 + 3]);
        const f4 td0 = *reinterpret_cast<const f4*>(s_tD[i * 4 + 0]);
        const f4 td1 = *reinterpret_cast<const f4*>(s_tD[i * 4 + 1]);
        const f4 td2 = *reinterpret_cast<const f4*>(s_tD[i * 4 + 2]);
        const f4 td3 = *reinterpret_cast<const f4*>(s_tD[i * 4 + 3]);
        const f4 te0 = *reinterpret_cast<const f4*>(s_tE[i * 4 + 0]);
        const f4 te1 = *reinterpret_cast<const f4*>(s_tE[i * 4 + 1]);
        const f4 te2 = *reinterpret_cast<const f4*>(s_tE[i * 4 + 2]);
        const f4 te3 = *reinterpret_cast<const f4*>(s_tE[i * 4 + 3]);
        const f4 wb  = *(reinterpret_cast<const f4*>(s_wB) + i);

        float den = bv.x * wb.x + bv.y * wb.y + bv.z * wb.z + bv.w * wb.w;
        if (den == 0.f) den = 1.f;
        const float inv = 1.0f / den;

        const f4 xyz = bv.x  * tb0 + bv.y  * tb1 + bv.z  * tb2 + bv.w  * tb3;
        const f4 du  = bv.x  * td0 + bv.y  * td1 + bv.z  * td2 + bv.w  * td3;
        const f4 dv  = dbv.x * tb0 + dbv.y * tb1 + dbv.z * tb2 + dbv.w * tb3;
        const f4 eu  = bv.x  * te0 + bv.y  * te1 + bv.z  * te2 + bv.w  * te3;
        const f4 ev  = ddbv.x* tb0 + ddbv.y* tb1 + ddbv.z* tb2 + ddbv.w* tb3;

        const float x0 = xyz.x * inv, x1 = xyz.y * inv, x2 = xyz.z * inv;
        const float du0 = du.x * inv, du1 = du.y * inv, du2 = du.z * inv;
        const float dv0 = dv.x * inv, dv1 = dv.y * inv, dv2 = dv.z * inv;

        const float cx = du1 * dv2 - du2 * dv1;
        const float cy = du2 * dv0 - du0 * dv2;
        const float cz = du0 * dv1 - du1 * dv0;

        // L1-normalize is mathematically dead (only the L2-unit direction
        // feeds the quaternion): n = cross / ||cross||_2.
        const float clen = sqrtf(cx * cx + cy * cy + cz * cz);
        const float rcl  = 1.0f / fmaxf(clen, 1e-20f);
        const float nx = cx * rcl, ny = cy * rcl, nz = cz * rcl;
        const float qw = 1.f + nz, qx = -ny, qy = nx;
        float qn = sqrtf(qw * qw + qx * qx + qy * qy);
        qn = fmaxf(qn, 1e-12f);
        const float rqn = 1.0f / qn;

        nt_store4(out + N7 + n * 4, qw * rqn, qx * rqn, qy * rqn, 0.f);

        if (t < 64)
            nt_copy4(out + N3 + n0 + 4 * t, opac + n0 + 4 * t);

        const float sx  = du0 * du0 + du1 * du1 + du2 * du2 + 10.f;
        const float sy  = dv0 * dv0 + dv1 * dv1 + dv2 * dv2 + 10.f;
        const float cvx = (eu.x + eu.y + eu.z) * inv;
        const float cvy = (ev.x + ev.y + ev.z) * inv;

        const float factor = ws[a] * (1.0f / 1024.0f) * (1.0f / 1024.0f);
        const float sp0 = spar[a * 2 + 0], sp1 = spar[a * 2 + 1];
        const float sf0 = factor * sp0;
        const float sf1 = factor * sp1;
        const float sf2 = factor * 1e-16f;

        s_xyz[t * 3 + 0] = x0;
        s_xyz[t * 3 + 1] = x1;
        s_xyz[t * 3 + 2] = x2;
        s_scl[t * 3 + 0] = 0.5f * __logf(fabsf(sf0 * sx)) - __logf(fabsf(cvx) + 10.f);
        s_scl[t * 3 + 1] = 0.5f * __logf(fabsf(sf1 * sy)) - __logf(fabsf(cvy) + 10.f);
        s_scl[t * 3 + 2] = 0.5f * __logf(fabsf(sf2 * 10.f)) - __logf(11.f);
    }
    __syncthreads();

    if (t < 192) {
        nt_copy4(out + n0 * 3 + 4 * t, s_xyz + 4 * t);
        nt_copy4(out + N4 + n0 * 3 + 4 * t, s_scl + 4 * t);
    }

    // ---- SH stage 2 ----
    float* __restrict__ outp =
        out + 11L * NTOT + ((long)a * 12288 + q * 3072) * 4;

    #pragma unroll
    for (int k = 0; k < 12; ++k) {
        const unsigned f = t + (k << 8);
        const unsigned p = f / 12u;
        const unsigned c = f - p * 12u;
        const int i = p >> 5;
        const int j = p & 31;

        const float4 bv = *reinterpret_cast<const float4*>(g_bv[j]);
        const float* base = &s_tmp[i * 208 + c * 4];

        const float4 t0 = *reinterpret_cast<const float4*>(base + 0 * 52);
        const float4 t1 = *reinterpret_cast<const float4*>(base + 1 * 52);
        const float4 t2 = *reinterpret_cast<const float4*>(base + 2 * 52);
        const float4 t3 = *reinterpret_cast<const float4*>(base + 3 * 52);

        nt_store4(outp + f * 4,
            bv.x * t0.x + bv.y * t1.x + bv.z * t2.x + bv.w * t3.x,
            bv.x * t0.y + bv.y * t1.y + bv.z * t2.y + bv.w * t3.y,
            bv.x * t0.z + bv.y * t1.z + bv.z * t2.z + bv.w * t3.z,
            bv.x * t0.w + bv.y * t1.w + bv.z * t2.w + bv.w * t3.w);
    }
}

extern "C" void kernel_launch(void* const* d_in, const int* in_sizes, int n_in,
                              void* d_out, int out_size, void* d_ws, size_t ws_size,
                              hipStream_t stream) {
    const float* cp      = (const float*)d_in[0];
    const float* Wt      = (const float*)d_in[1];
    const float* sh_dc   = (const float*)d_in[2];
    const float* sh_rest = (const float*)d_in[3];
    const float* spar    = (const float*)d_in[4];
    const float* opac    = (const float*)d_in[5];
    const float* b_u     = (const float*)d_in[6];
    const float* b_v     = (const float*)d_in[7];
    const float* db_u    = (const float*)d_in[8];
    const float* db_v    = (const float*)d_in[9];
    const float* ddb_u   = (const float*)d_in[10];
    const float* ddb_v   = (const float*)d_in[11];
    float* out = (float*)d_out;
    float* ws  = (float*)d_ws;

    hipLaunchKernelGGL(area_kernel, dim3(NPATCH), dim3(256), 0, stream,
                       cp, Wt, b_u, b_v, db_u, db_v, ws);
    hipLaunchKernelGGL(fused_kernel, dim3(NPATCH * 4), dim3(256), 0, stream,
                       cp, Wt, sh_dc, sh_rest, spar, opac,
                       b_u, b_v, db_u, db_v, ddb_u, ddb_v, ws, out);
}

// Round 11
// 103.593 us; speedup vs baseline: 1.4506x; 1.0467x over previous
//
#include <hip/hip_runtime.h>
#include <math.h>

#define NPATCH 2048
#define NPTS 1024
#define NTOT (NPATCH * NPTS)

using f4 = __attribute__((ext_vector_type(4))) float;

__device__ __forceinline__ void nt_store4(float* p, float a, float b, float c, float d) {
    f4 v = {a, b, c, d};
    __builtin_nontemporal_store(v, reinterpret_cast<f4*>(p));
}
__device__ __forceinline__ void nt_copy4(float* dst, const float* src) {
    f4 v = *reinterpret_cast<const f4*>(src);
    __builtin_nontemporal_store(v, reinterpret_cast<f4*>(dst));
}
__device__ __forceinline__ void nt_store1(float* p, float v) {
    __builtin_nontemporal_store(v, p);
}

// ---------------------------------------------------------------------------
// Single mega-kernel: 8192 blocks x 256 threads, one quarter-patch each.
//   staging -> stage1 (tB/tD full 32 rows, tE local, wB, SH-tmp) ->
//   in-block FULL-patch area recompute (4 pts/thread, deterministic) ->
//   geometry stage2 (direct NT stores) -> SH stage2 (NT stores).
// Area is recomputed identically by all 4 blocks of a patch (no cross-block
// dependency, no second dispatch, no ws).
// ---------------------------------------------------------------------------
__global__ __launch_bounds__(256) void mega_kernel(
    const float* __restrict__ cp,       // [P,4,4,3]
    const float* __restrict__ Wt,       // [P,4,4]
    const float* __restrict__ sh_dc,    // [P,4,4,1,3]
    const float* __restrict__ sh_rest,  // [P,4,4,15,3]
    const float* __restrict__ spar,     // [P,2]
    const float* __restrict__ opac,     // [N,1]
    const float* __restrict__ b_u,      // [P,32,4]
    const float* __restrict__ b_v,
    const float* __restrict__ db_u,
    const float* __restrict__ db_v,
    const float* __restrict__ ddb_u,
    const float* __restrict__ ddb_v,
    float* __restrict__ out)
{
    const int blk = blockIdx.x;
    const int a = blk >> 2, q = blk & 3;
    const int t = threadIdx.x;

    __shared__ float s_W[16];
    __shared__ __align__(16) float s_wcp4[16][4];
    __shared__ __align__(16) float s_bu[32][4];     // full patch rows
    __shared__ __align__(16) float s_dbu[32][4];    // full patch rows
    __shared__ __align__(16) float s_ddbu[8][4];    // this quarter's rows
    __shared__ __align__(16) float s_bv[32][4];
    __shared__ __align__(16) float s_dbv[32][4];
    __shared__ __align__(16) float s_ddbv[32][4];
    __shared__ __align__(16) float s_tB[128][4];    // [i*4+l][m], i = 0..31
    __shared__ __align__(16) float s_tD[128][4];
    __shared__ __align__(16) float s_tE[32][4];     // local 8 rows
    __shared__ __align__(16) float s_wB[128];
    __shared__ __align__(16) float s_sh[16][48];
    __shared__ __align__(16) float s_tmp[8 * 208];  // [i][l][cq]: i*208+l*52+cq*4
    __shared__ float s_red[4];
    __shared__ float s_area;

    // ---- staging ----
    if (t < 16) {
        const float w = Wt[a * 16 + t];
        s_W[t] = w;
        s_wcp4[t][0] = cp[a * 48 + t * 3 + 0] * w;
        s_wcp4[t][1] = cp[a * 48 + t * 3 + 1] * w;
        s_wcp4[t][2] = cp[a * 48 + t * 3 + 2] * w;
        s_wcp4[t][3] = 0.f;
    }
    if (t < 128) {
        s_bu  [t >> 2][t & 3] = b_u  [a * 128 + t];
        s_dbu [t >> 2][t & 3] = db_u [a * 128 + t];
        s_bv  [t >> 2][t & 3] = b_v  [a * 128 + t];
        s_dbv [t >> 2][t & 3] = db_v [a * 128 + t];
        s_ddbv[t >> 2][t & 3] = ddb_v[a * 128 + t];
    }
    if (t < 32)
        s_ddbu[t >> 2][t & 3] = ddb_u[a * 128 + q * 32 + t];
    for (int idx = t; idx < 768; idx += 256) {
        const int kl = idx / 48, c = idx - kl * 48;
        s_sh[kl][c] = (c < 3) ? sh_dc[a * 48 + kl * 3 + c]
                              : sh_rest[a * 720 + kl * 45 + (c - 3)];
    }
    __syncthreads();

    // ---- stage 1 ----
    if (t < 128) {          // tB + wB for all 32 u-rows
        const int i = t >> 2, l = t & 3;
        f4 acc = {0.f, 0.f, 0.f, 0.f};
        float wa = 0.f;
        #pragma unroll
        for (int k = 0; k < 4; ++k) {
            const float b = s_bu[i][k];
            acc += b * *reinterpret_cast<const f4*>(s_wcp4[k * 4 + l]);
            wa  += b * s_W[k * 4 + l];
        }
        *reinterpret_cast<f4*>(s_tB[t]) = acc;
        s_wB[t] = wa;
    } else {                // tD for all 32 u-rows
        const int tt = t - 128, i = tt >> 2, l = tt & 3;
        f4 acc = {0.f, 0.f, 0.f, 0.f};
        #pragma unroll
        for (int k = 0; k < 4; ++k)
            acc += s_dbu[i][k] * *reinterpret_cast<const f4*>(s_wcp4[k * 4 + l]);
        *reinterpret_cast<f4*>(s_tD[tt]) = acc;
    }
    if (t < 32) {           // tE for this quarter's 8 rows
        const int i = t >> 2, l = t & 3;
        f4 acc = {0.f, 0.f, 0.f, 0.f};
        #pragma unroll
        for (int k = 0; k < 4; ++k)
            acc += s_ddbu[i][k] * *reinterpret_cast<const f4*>(s_wcp4[k * 4 + l]);
        *reinterpret_cast<f4*>(s_tE[t]) = acc;
    }
    // SH stage1: tmp[i][l][cq] for this quarter's 8 rows (384 float4)
    #pragma unroll
    for (int r = 0; r < 2; ++r) {
        const int e4 = t + r * 256;
        if (e4 < 384) {
            const int i = e4 / 48, rem = e4 - i * 48;
            const int l = rem / 12, cq = rem - l * 12;
            float ax = 0.f, ay = 0.f, az = 0.f, aw = 0.f;
            #pragma unroll
            for (int k = 0; k < 4; ++k) {
                const float w = s_bu[q * 8 + i][k];
                const float4 v = *reinterpret_cast<const float4*>(&s_sh[k * 4 + l][cq * 4]);
                ax += w * v.x; ay += w * v.y; az += w * v.z; aw += w * v.w;
            }
            *reinterpret_cast<float4*>(&s_tmp[i * 208 + l * 52 + cq * 4]) =
                make_float4(ax, ay, az, aw);
        }
    }
    __syncthreads();

    // ---- full-patch area pass: 4 points/thread, identical in all 4 blocks ----
    const int j = t & 31;
    const f4 bvJ  = *reinterpret_cast<const f4*>(s_bv[j]);
    const f4 dbvJ = *reinterpret_cast<const f4*>(s_dbv[j]);
    {
        float acc = 0.f;
        #pragma unroll
        for (int s2 = 0; s2 < 4; ++s2) {
            const int i = (t >> 5) + 8 * s2;
            const f4 tb0 = *reinterpret_cast<const f4*>(s_tB[i * 4 + 0]);
            const f4 tb1 = *reinterpret_cast<const f4*>(s_tB[i * 4 + 1]);
            const f4 tb2 = *reinterpret_cast<const f4*>(s_tB[i * 4 + 2]);
            const f4 tb3 = *reinterpret_cast<const f4*>(s_tB[i * 4 + 3]);
            const f4 td0 = *reinterpret_cast<const f4*>(s_tD[i * 4 + 0]);
            const f4 td1 = *reinterpret_cast<const f4*>(s_tD[i * 4 + 1]);
            const f4 td2 = *reinterpret_cast<const f4*>(s_tD[i * 4 + 2]);
            const f4 td3 = *reinterpret_cast<const f4*>(s_tD[i * 4 + 3]);
            const f4 wb  = *(reinterpret_cast<const f4*>(s_wB) + i);

            float den = bvJ.x * wb.x + bvJ.y * wb.y + bvJ.z * wb.z + bvJ.w * wb.w;
            if (den == 0.f) den = 1.f;
            const float inv = 1.0f / den;

            const f4 du = bvJ.x  * td0 + bvJ.y  * td1 + bvJ.z  * td2 + bvJ.w  * td3;
            const f4 dv = dbvJ.x * tb0 + dbvJ.y * tb1 + dbvJ.z * tb2 + dbvJ.w * tb3;

            const float cx = du.y * dv.z - du.z * dv.y;
            const float cy = du.z * dv.x - du.x * dv.z;
            const float cz = du.x * dv.y - du.y * dv.x;
            acc += sqrtf(cx * cx + cy * cy + cz * cz) * inv * inv;
        }
        #pragma unroll
        for (int off = 32; off > 0; off >>= 1)
            acc += __shfl_down(acc, off, 64);
        if ((t & 63) == 0) s_red[t >> 6] = acc;
    }
    __syncthreads();
    if (t == 0) s_area = s_red[0] + s_red[1] + s_red[2] + s_red[3];
    __syncthreads();

    const long N3 = 3L * NTOT, N4 = 4L * NTOT, N7 = 7L * NTOT;
    const long n0 = (long)a * NPTS + q * 256;
    const long n  = n0 + t;

    // ---- geometry stage 2 (direct NT stores) ----
    {
        const int gi = q * 8 + (t >> 5);        // global u-row
        const f4 ddbvJ = *reinterpret_cast<const f4*>(s_ddbv[j]);

        const f4 tb0 = *reinterpret_cast<const f4*>(s_tB[gi * 4 + 0]);
        const f4 tb1 = *reinterpret_cast<const f4*>(s_tB[gi * 4 + 1]);
        const f4 tb2 = *reinterpret_cast<const f4*>(s_tB[gi * 4 + 2]);
        const f4 tb3 = *reinterpret_cast<const f4*>(s_tB[gi * 4 + 3]);
        const f4 td0 = *reinterpret_cast<const f4*>(s_tD[gi * 4 + 0]);
        const f4 td1 = *reinterpret_cast<const f4*>(s_tD[gi * 4 + 1]);
        const f4 td2 = *reinterpret_cast<const f4*>(s_tD[gi * 4 + 2]);
        const f4 td3 = *reinterpret_cast<const f4*>(s_tD[gi * 4 + 3]);
        const int il = t >> 5;                  // local row for tE
        const f4 te0 = *reinterpret_cast<const f4*>(s_tE[il * 4 + 0]);
        const f4 te1 = *reinterpret_cast<const f4*>(s_tE[il * 4 + 1]);
        const f4 te2 = *reinterpret_cast<const f4*>(s_tE[il * 4 + 2]);
        const f4 te3 = *reinterpret_cast<const f4*>(s_tE[il * 4 + 3]);
        const f4 wb  = *(reinterpret_cast<const f4*>(s_wB) + gi);

        float den = bvJ.x * wb.x + bvJ.y * wb.y + bvJ.z * wb.z + bvJ.w * wb.w;
        if (den == 0.f) den = 1.f;
        const float inv = 1.0f / den;

        const f4 xyz = bvJ.x  * tb0 + bvJ.y  * tb1 + bvJ.z  * tb2 + bvJ.w  * tb3;
        const f4 du  = bvJ.x  * td0 + bvJ.y  * td1 + bvJ.z  * td2 + bvJ.w  * td3;
        const f4 dv  = dbvJ.x * tb0 + dbvJ.y * tb1 + dbvJ.z * tb2 + dbvJ.w * tb3;
        const f4 eu  = bvJ.x  * te0 + bvJ.y  * te1 + bvJ.z  * te2 + bvJ.w  * te3;
        const f4 ev  = ddbvJ.x* tb0 + ddbvJ.y* tb1 + ddbvJ.z* tb2 + ddbvJ.w* tb3;

        const float x0 = xyz.x * inv, x1 = xyz.y * inv, x2 = xyz.z * inv;
        const float du0 = du.x * inv, du1 = du.y * inv, du2 = du.z * inv;
        const float dv0 = dv.x * inv, dv1 = dv.y * inv, dv2 = dv.z * inv;

        const float cx = du1 * dv2 - du2 * dv1;
        const float cy = du2 * dv0 - du0 * dv2;
        const float cz = du0 * dv1 - du1 * dv0;

        // n = cross / ||cross||_2  (L1 normalize is mathematically dead)
        const float clen = sqrtf(cx * cx + cy * cy + cz * cz);
        const float rcl  = 1.0f / fmaxf(clen, 1e-20f);
        const float nx = cx * rcl, ny = cy * rcl, nz = cz * rcl;
        const float qw = 1.f + nz, qx = -ny, qy = nx;
        float qn = sqrtf(qw * qw + qx * qx + qy * qy);
        qn = fmaxf(qn, 1e-12f);
        const float rqn = 1.0f / qn;

        nt_store4(out + N7 + n * 4, qw * rqn, qx * rqn, qy * rqn, 0.f);
        nt_store1(out + n * 3 + 0, x0);
        nt_store1(out + n * 3 + 1, x1);
        nt_store1(out + n * 3 + 2, x2);

        if (t < 64)
            nt_copy4(out + N3 + n0 + 4 * t, opac + n0 + 4 * t);

        const float sx  = du0 * du0 + du1 * du1 + du2 * du2 + 10.f;
        const float sy  = dv0 * dv0 + dv1 * dv1 + dv2 * dv2 + 10.f;
        const float cvx = (eu.x + eu.y + eu.z) * inv;
        const float cvy = (ev.x + ev.y + ev.z) * inv;

        const float factor = s_area * (1.0f / 1024.0f) * (1.0f / 1024.0f);
        const float sp0 = spar[a * 2 + 0], sp1 = spar[a * 2 + 1];
        const float sf0 = factor * sp0;
        const float sf1 = factor * sp1;
        const float sf2 = factor * 1e-16f;

        nt_store1(out + N4 + n * 3 + 0,
                  0.5f * __logf(fabsf(sf0 * sx)) - __logf(fabsf(cvx) + 10.f));
        nt_store1(out + N4 + n * 3 + 1,
                  0.5f * __logf(fabsf(sf1 * sy)) - __logf(fabsf(cvy) + 10.f));
        nt_store1(out + N4 + n * 3 + 2,
                  0.5f * __logf(fabsf(sf2 * 10.f)) - __logf(11.f));
    }

    // ---- SH stage 2 (no barrier needed: s_tmp synced at stage1) ----
    float* __restrict__ outp =
        out + 11L * NTOT + ((long)a * 12288 + q * 3072) * 4;

    #pragma unroll
    for (int k = 0; k < 12; ++k) {
        const unsigned f = t + (k << 8);
        const unsigned p = f / 12u;
        const unsigned c = f - p * 12u;
        const int i = p >> 5;
        const int jj = p & 31;

        const float4 bv = *reinterpret_cast<const float4*>(s_bv[jj]);
        const float* base = &s_tmp[i * 208 + c * 4];

        const float4 t0 = *reinterpret_cast<const float4*>(base + 0 * 52);
        const float4 t1 = *reinterpret_cast<const float4*>(base + 1 * 52);
        const float4 t2 = *reinterpret_cast<const float4*>(base + 2 * 52);
        const float4 t3 = *reinterpret_cast<const float4*>(base + 3 * 52);

        nt_store4(outp + f * 4,
            bv.x * t0.x + bv.y * t1.x + bv.z * t2.x + bv.w * t3.x,
            bv.x * t0.y + bv.y * t1.y + bv.z * t2.y + bv.w * t3.y,
            bv.x * t0.z + bv.y * t1.z + bv.z * t2.z + bv.w * t3.z,
            bv.x * t0.w + bv.y * t1.w + bv.z * t2.w + bv.w * t3.w);
    }
}

extern "C" void kernel_launch(void* const* d_in, const int* in_sizes, int n_in,
                              void* d_out, int out_size, void* d_ws, size_t ws_size,
                              hipStream_t stream) {
    const float* cp      = (const float*)d_in[0];
    const float* Wt      = (const float*)d_in[1];
    const float* sh_dc   = (const float*)d_in[2];
    const float* sh_rest = (const float*)d_in[3];
    const float* spar    = (const float*)d_in[4];
    const float* opac    = (const float*)d_in[5];
    const float* b_u     = (const float*)d_in[6];
    const float* b_v     = (const float*)d_in[7];
    const float* db_u    = (const float*)d_in[8];
    const float* db_v    = (const float*)d_in[9];
    const float* ddb_u   = (const float*)d_in[10];
    const float* ddb_v   = (const float*)d_in[11];
    float* out = (float*)d_out;

    hipLaunchKernelGGL(mega_kernel, dim3(NPATCH * 4), dim3(256), 0, stream,
                       cp, Wt, sh_dc, sh_rest, spar, opac,
                       b_u, b_v, db_u, db_v, ddb_u, ddb_v, out);
}